// Round 13
// baseline (679.342 us; speedup 1.0000x reference)
//
#include <hip/hip_runtime.h>
#include <hip/hip_bf16.h>
#include <hip/hip_cooperative_groups.h>
#include <math.h>

namespace cg = cooperative_groups;

#define DIM 128
#define TOPK 128
#define CAP 4096
#define SCAN_B 256
#define HSIZE 16384
#define HSHIFT 18          // f2k >> 18 -> 14-bit bin
#define HMUL 10937u        // odd -> bijective mod 2^14
#define MEGA_B 512         // cooperative grid: 2 blocks/CU -> ample co-residency margin

typedef __attribute__((ext_vector_type(8))) short bf16x8;
typedef __attribute__((ext_vector_type(4))) float f32x4;

__device__ __forceinline__ unsigned f2k(float f) {
    unsigned b = __float_as_uint(f);
    return (b & 0x80000000u) ? ~b : (b | 0x80000000u);
}

__device__ __forceinline__ unsigned hidx(unsigned bin) {
    return (bin * HMUL) & (HSIZE - 1u);
}

__device__ __forceinline__ unsigned bf16rn(float v) {
    unsigned u = __float_as_uint(v);
    u += 0x7fffu + ((u >> 16) & 1u);
    return u >> 16;
}

__device__ __forceinline__ unsigned pack2bf(float lo, float hi) {
    return (bf16rn(hi) << 16) | bf16rn(lo);
}

// one u64 atomic per edge: [63:40] count, [39:0] fixed-point weight sum (2^-32).
__device__ __forceinline__ void deg_edge(const int* __restrict__ ei, const float* __restrict__ ew,
                                         unsigned long long* __restrict__ packed,
                                         int* __restrict__ eseq, int ne, int e) {
    int c = ei[ne + e];
    float w = ew[e];
    unsigned long long fx = (unsigned long long)((double)w * 4294967296.0);
    unsigned long long old = atomicAdd(&packed[c], (1ull << 40) | fx);
    eseq[e] = (int)(old >> 40);
}

__device__ __forceinline__ bool pick_deg(int bid, int degB, int T, int* mi, int* di) {
    long long a = (long long)bid * degB;
    int before = (int)(a / T);
    if ((int)((a + degB) / T) > before) { *di = before; return true; }
    *mi = bid - before;
    return false;
}

// block 0: ||p|| ; other blocks: zero packed + hist + counter
__global__ void k_pnorm_zero(const float* __restrict__ p, float* __restrict__ pinv,
                             unsigned long long* __restrict__ packed,
                             unsigned* __restrict__ hist, unsigned* __restrict__ counter, int n) {
    if (blockIdx.x == 0) {
        __shared__ float s[DIM];
        int t = threadIdx.x;
        float v = p[t];
        s[t] = v * v;
        __syncthreads();
        for (int off = 64; off > 0; off >>= 1) {
            if (t < off) s[t] += s[t + off];
            __syncthreads();
        }
        if (t == 0) pinv[0] = 1.0f / sqrtf(s[0]);
    } else {
        int base = ((int)blockIdx.x - 1) * 1024 + (int)threadIdx.x;
        if (blockIdx.x == 1 && threadIdx.x == 0) counter[0] = 0u;
#pragma unroll
        for (int j = 0; j < 8; ++j) {
            int i = base + j * 128;
            if (i < n) packed[i] = 0ull;
            if (i < HSIZE) hist[i] = 0u;
        }
    }
}

// 16 lanes per node (2x float4 each): score + spread-hist bin, + deg slice
__global__ void k_score_deg(const float* __restrict__ x, const float* __restrict__ p,
                            const float* __restrict__ pinv, float* __restrict__ score,
                            unsigned* __restrict__ hist, int n,
                            int degB, const int* __restrict__ ei, const float* __restrict__ ew,
                            unsigned long long* __restrict__ packed, int* __restrict__ eseq,
                            int e0, int e1, int ne) {
    int mi, di;
    if (pick_deg((int)blockIdx.x, degB, (int)gridDim.x, &mi, &di)) {
        int e = e0 + di * 256 + (int)threadIdx.x;
        if (e < e1) deg_edge(ei, ew, packed, eseq, ne, e);
        return;
    }
    int gid = mi * 256 + (int)threadIdx.x;
    int node = gid >> 4, lane = gid & 15;
    if (node >= n) return;
    const float4* xr = (const float4*)(x) + (size_t)node * 32;
    const float4* p4 = (const float4*)p;
    float4 a0 = xr[lane * 2], a1 = xr[lane * 2 + 1];
    float4 b0 = p4[lane * 2], b1 = p4[lane * 2 + 1];
    float acc = a0.x * b0.x + a0.y * b0.y + a0.z * b0.z + a0.w * b0.w +
                a1.x * b1.x + a1.y * b1.y + a1.z * b1.z + a1.w * b1.w;
#pragma unroll
    for (int m = 8; m >= 1; m >>= 1) acc += __shfl_xor(acc, m, 16);
    if (lane == 0) {
        float s = acc * pinv[0];
        score[node] = s;
        atomicAdd(&hist[hidx(f2k(s) >> HSHIFT)], 1u);
    }
}

// ======================= cooperative mega-kernel path =======================
__global__ __launch_bounds__(256, 2) void k_mega(
    const float* __restrict__ x, const int* __restrict__ ei,
    const float* __restrict__ ew, unsigned* __restrict__ hist,
    unsigned* __restrict__ binfo, const float* __restrict__ score,
    unsigned* __restrict__ counter, float* __restrict__ cval,
    int* __restrict__ cidx, int* __restrict__ perm, float* __restrict__ vals,
    const float* __restrict__ W0, const float* __restrict__ w_ih,
    const float* __restrict__ w_hh, const float* __restrict__ b_ih,
    const float* __restrict__ b_hh, unsigned short* __restrict__ WhT,
    unsigned short* __restrict__ xwh, unsigned long long* __restrict__ packed,
    int* __restrict__ eseq, float* __restrict__ dinv, int* __restrict__ cnt,
    int* __restrict__ bsum, int* __restrict__ offs, int2* __restrict__ edata,
    int n, int ne, int eA, int eB, int eC, int eD, int eE) {
    cg::grid_group grid = cg::this_grid();
    __shared__ __align__(16) char smem[16384];
    int bid = (int)blockIdx.x, tid = (int)threadIdx.x, GB = (int)gridDim.x;

    // ---- phase A: findbin (block 0) + deg [eA,eB) ----
    if (bid == 0) {
        unsigned* csum = (unsigned*)smem;
        unsigned s = 0;
        for (int j = 0; j < 64; ++j) s += hist[hidx((unsigned)(tid * 64 + j))];
        csum[tid] = s;
        __syncthreads();
        for (int off = 1; off < 256; off <<= 1) {
            unsigned v = (tid + off < 256) ? csum[tid + off] : 0u;
            __syncthreads();
            csum[tid] += v;
            __syncthreads();
        }
        unsigned run = (tid + 1 < 256) ? csum[tid + 1] : 0u;
        for (int j = 63; j >= 0; --j) {
            unsigned h = hist[hidx((unsigned)(tid * 64 + j))];
            if (h > 0u && run < (unsigned)TOPK && run + h >= (unsigned)TOPK) {
                binfo[0] = (unsigned)(tid * 64 + j);
                binfo[1] = run;
            }
            run += h;
        }
    } else {
        for (int e = eA + (bid - 1) * 256 + tid; e < eB; e += (GB - 1) * 256)
            deg_edge(ei, ew, packed, eseq, ne, e);
    }
    grid.sync();

    // ---- phase B: collect (grid-stride over CB blocks) + deg [eB,eC) ----
    {
        int CB = GB - 64; if (CB < 1) CB = 1;
        if (bid < CB) {
            for (int i = bid * 256 + tid; i < n; i += CB * 256) {
                float s = score[i];
                if ((f2k(s) >> HSHIFT) >= binfo[0]) {
                    unsigned pos = atomicAdd(counter, 1u);
                    if (pos < CAP) { cval[pos] = s; cidx[pos] = i; }
                }
            }
        } else {
            for (int e = eB + (bid - CB) * 256 + tid; e < eC; e += (GB - CB) * 256)
                deg_edge(ei, ew, packed, eseq, ne, e);
        }
    }
    grid.sync();

    // ---- phase C: rank (16 blocks) + deg [eC,eD) ----
    if (bid < 16) {
        int i = bid * 256 + tid;
        unsigned cc = counter[0];
        int m = (cc < (unsigned)CAP) ? (int)cc : CAP;
        if (i < m) {
            float v = cval[i]; int id = cidx[i];
            int rank = 0;
            for (int j = 0; j < m; ++j) {
                float vj = cval[j]; int ij = cidx[j];
                if (vj > v || (vj == v && ij < id)) ++rank;
            }
            if (rank < TOPK) { perm[rank] = id; vals[rank] = v; }
        }
    } else {
        for (int e = eC + (bid - 16) * 256 + tid; e < eD; e += (GB - 16) * 256)
            deg_edge(ei, ew, packed, eseq, ne, e);
    }
    grid.sync();

    // ---- phase D: gru (64 blocks, 2 rows each) + deg [eD,eE) ----
    if (bid < 64) {
        float* sx = (float*)smem;
        float* sh = sx + 256;
        int half = tid >> 7, c = tid & 127;
        int i = bid * 2 + half;
        sx[half * DIM + c] = x[(size_t)perm[i] * DIM + c] * tanhf(vals[i]);
        sh[half * DIM + c] = W0[i * DIM + c];
        __syncthreads();
        float gr = b_ih[c], gz = b_ih[DIM + c], gn = b_ih[2 * DIM + c];
        float hr = b_hh[c], hz = b_hh[DIM + c], hn = b_hh[2 * DIM + c];
        const float* wr = w_ih + (size_t)c * DIM;
        const float* wz = w_ih + (size_t)(DIM + c) * DIM;
        const float* wn = w_ih + (size_t)(2 * DIM + c) * DIM;
        const float* ur = w_hh + (size_t)c * DIM;
        const float* uz = w_hh + (size_t)(DIM + c) * DIM;
        const float* un = w_hh + (size_t)(2 * DIM + c) * DIM;
        for (int d = 0; d < DIM; ++d) {
            float xd = sx[half * DIM + d], hd = sh[half * DIM + d];
            gr += xd * wr[d]; gz += xd * wz[d]; gn += xd * wn[d];
            hr += hd * ur[d]; hz += hd * uz[d]; hn += hd * un[d];
        }
        float r = 1.0f / (1.0f + expf(-(gr + hr)));
        float z = 1.0f / (1.0f + expf(-(gz + hz)));
        float nn = tanhf(gn + r * hn);
        float wv = (1.0f - z) * nn + z * sh[half * DIM + c];
        WhT[(size_t)c * DIM + i] = (unsigned short)bf16rn(wv);
    } else {
        for (int e = eD + (bid - 64) * 256 + tid; e < eE; e += (GB - 64) * 256)
            deg_edge(ei, ew, packed, eseq, ne, e);
    }
    grid.sync();

    // ---- phase E: xw MFMA (384 blocks grid-stride over tiles) + deg [eE,ne) ----
    {
        int EB = 384; if (EB > GB - 32) EB = GB - 32;
        if (bid < EB) {
            unsigned short* xs = (unsigned short*)smem;
            int nTr = (n + 63) >> 6;
            int nTiles = nTr * 2;
            for (int tile = bid; tile < nTiles; tile += EB) {
                int r0 = (tile % nTr) * 64;
                int c0 = (tile / nTr) * 64;
                {
                    int r = tid >> 2;
                    int row = r0 + r; if (row >= n) row = n - 1;
                    const float4* xr = (const float4*)(x + (size_t)row * DIM);
#pragma unroll
                    for (int j = 0; j < 4; ++j) {
                        int g = (tid & 3) + 4 * j;
                        float4 lo = xr[g * 2], hi = xr[g * 2 + 1];
                        uint4 o;
                        o.x = pack2bf(lo.x, lo.y); o.y = pack2bf(lo.z, lo.w);
                        o.z = pack2bf(hi.x, hi.y); o.w = pack2bf(hi.z, hi.w);
                        *(uint4*)&xs[r * DIM + ((g ^ (r & 7)) << 3)] = o;
                    }
                }
                __syncthreads();
                int wid = tid >> 6, lane = tid & 63;
                int lr = wid * 16 + (lane & 15);
                int kg = lane >> 4;
                int cA = lane & 15;
                f32x4 acc[4] = {{0.f,0.f,0.f,0.f},{0.f,0.f,0.f,0.f},
                                {0.f,0.f,0.f,0.f},{0.f,0.f,0.f,0.f}};
                const bf16x8* wt = (const bf16x8*)WhT;
#pragma unroll
                for (int q = 0; q < 4; ++q) {
                    bf16x8 a = *(const bf16x8*)&xs[lr * DIM + (((q * 4 + kg) ^ (lr & 7)) << 3)];
#pragma unroll
                    for (int ct = 0; ct < 4; ++ct) {
                        bf16x8 b = wt[(size_t)(c0 + ct * 16 + cA) * 16 + q * 4 + kg];
                        acc[ct] = __builtin_amdgcn_mfma_f32_16x16x32_bf16(a, b, acc[ct], 0, 0, 0);
                    }
                }
                int orow = r0 + wid * 16 + (lane >> 4) * 4;
#pragma unroll
                for (int reg = 0; reg < 4; ++reg) {
                    int row = orow + reg;
                    if (row < n) {
                        unsigned short* dst = xwh + (size_t)row * DIM + c0 + cA;
#pragma unroll
                        for (int ct = 0; ct < 4; ++ct)
                            dst[ct * 16] = (unsigned short)bf16rn(acc[ct][reg]);
                    }
                }
                __syncthreads();
            }
        } else {
            for (int e = eE + (bid - EB) * 256 + tid; e < ne; e += (GB - EB) * 256)
                deg_edge(ei, ew, packed, eseq, ne, e);
        }
    }
    grid.sync();

    // ---- phase F: unpack packed -> dinv/cnt + per-block partial sums ----
    if (bid < SCAN_B) {
        int* red = (int*)smem;
        int chunk = (n + SCAN_B - 1) / SCAN_B;
        int lo = bid * chunk;
        int hi = lo + chunk; if (hi > n) hi = n;
        int s = 0;
        for (int i = lo + tid; i < hi; i += 256) {
            unsigned long long pk = packed[i];
            float sumw = (float)((double)(pk & ((1ull << 40) - 1ull)) * (1.0 / 4294967296.0));
            dinv[i] = rsqrtf(1.0f + sumw);
            int c = (int)(pk >> 40);
            cnt[i] = c;
            s += c;
        }
        red[tid] = s;
        __syncthreads();
        for (int off = 128; off > 0; off >>= 1) {
            if (tid < off) red[tid] += red[tid + off];
            __syncthreads();
        }
        if (tid == 0) bsum[bid] = red[0];
    }
    grid.sync();

    // ---- phase G: offs (256 blocks each locally scan bsum, write chunk) ----
    if (bid < SCAN_B) {
        int* sb = (int*)smem;
        int* red = (int*)(smem + 1024);
        sb[tid] = bsum[tid];
        __syncthreads();
        for (int off = 1; off < SCAN_B; off <<= 1) {
            int v = (tid >= off) ? sb[tid - off] : 0;
            __syncthreads();
            sb[tid] += v;
            __syncthreads();
        }
        int bbase = (bid > 0) ? sb[bid - 1] : 0;
        int total = sb[SCAN_B - 1];
        int chunk = (n + SCAN_B - 1) / SCAN_B;
        int lo = bid * chunk;
        int hi = lo + chunk; if (hi > n) hi = n;
        int tchunk = (chunk + 255) / 256;
        int tlo = lo + tid * tchunk;
        int thi = tlo + tchunk; if (thi > hi) thi = hi;
        int s = 0;
        for (int i = tlo; i < thi; ++i) s += cnt[i];
        red[tid] = s;
        __syncthreads();
        for (int off = 1; off < 256; off <<= 1) {
            int v = (tid >= off) ? red[tid - off] : 0;
            __syncthreads();
            red[tid] += v;
            __syncthreads();
        }
        int run = bbase + ((tid > 0) ? red[tid - 1] : 0);
        for (int i = tlo; i < thi; ++i) { offs[i] = run; run += cnt[i]; }
        if (bid == 0 && tid == 0) offs[n] = total;
    }
    grid.sync();

    // ---- phase H: fill edata (all blocks, grid-stride) ----
    for (int e = bid * 256 + tid; e < ne; e += GB * 256) {
        int r = ei[e], c = ei[ne + e];
        float nrm = dinv[r] * ew[e] * dinv[c];
        edata[offs[c] + eseq[e]] = make_int2(r, __float_as_int(nrm));
    }
}

// ======================= fallback multi-kernel path (proven R11) =======================
__global__ void k_findbin_deg(const unsigned* __restrict__ hist, unsigned* __restrict__ binfo, int k,
                              const int* __restrict__ ei, const float* __restrict__ ew,
                              unsigned long long* __restrict__ packed, int* __restrict__ eseq,
                              int e0, int e1, int ne) {
    if (blockIdx.x > 0) {
        int e = e0 + ((int)blockIdx.x - 1) * 1024 + (int)threadIdx.x;
        if (e < e1) deg_edge(ei, ew, packed, eseq, ne, e);
        return;
    }
    __shared__ unsigned csum[1024];
    int t = threadIdx.x;
    unsigned hv[16];
    unsigned s = 0;
#pragma unroll
    for (int j = 0; j < 16; ++j) {
        hv[j] = hist[hidx(t * 16 + j)];
        s += hv[j];
    }
    csum[t] = s;
    __syncthreads();
    for (int off = 1; off < 1024; off <<= 1) {
        unsigned v = (t + off < 1024) ? csum[t + off] : 0u;
        __syncthreads();
        csum[t] += v;
        __syncthreads();
    }
    unsigned run = (t + 1 < 1024) ? csum[t + 1] : 0u;
#pragma unroll
    for (int j = 15; j >= 0; --j) {
        unsigned h = hv[j];
        if (h > 0u && run < (unsigned)k && run + h >= (unsigned)k) {
            binfo[0] = (unsigned)(t * 16 + j);
            binfo[1] = run;
        }
        run += h;
    }
}

__global__ void k_collect_deg(const float* __restrict__ score, const unsigned* __restrict__ binfo,
                              unsigned* __restrict__ counter, float* __restrict__ cval,
                              int* __restrict__ cidx, int n,
                              int degB, const int* __restrict__ ei, const float* __restrict__ ew,
                              unsigned long long* __restrict__ packed, int* __restrict__ eseq,
                              int e0, int e1, int ne) {
    int mi, di;
    if (pick_deg((int)blockIdx.x, degB, (int)gridDim.x, &mi, &di)) {
        int e = e0 + di * 256 + (int)threadIdx.x;
        if (e < e1) deg_edge(ei, ew, packed, eseq, ne, e);
        return;
    }
    int i = mi * 256 + (int)threadIdx.x;
    if (i >= n) return;
    float s = score[i];
    if ((f2k(s) >> HSHIFT) >= binfo[0]) {
        unsigned pos = atomicAdd(counter, 1u);
        if (pos < CAP) { cval[pos] = s; cidx[pos] = i; }
    }
}

__global__ void k_rank_deg(const float* __restrict__ cval, const int* __restrict__ cidx,
                           const unsigned* __restrict__ counter, int* __restrict__ perm,
                           float* __restrict__ vals, int k,
                           int degB, const int* __restrict__ ei, const float* __restrict__ ew,
                           unsigned long long* __restrict__ packed, int* __restrict__ eseq,
                           int e0, int e1, int ne) {
    int mi, di;
    if (pick_deg((int)blockIdx.x, degB, (int)gridDim.x, &mi, &di)) {
        int e = e0 + di * 256 + (int)threadIdx.x;
        if (e < e1) deg_edge(ei, ew, packed, eseq, ne, e);
        return;
    }
    int i = mi * 256 + (int)threadIdx.x;
    unsigned cnt = counter[0];
    int m = (cnt < (unsigned)CAP) ? (int)cnt : CAP;
    if (i >= m) return;
    float v = cval[i]; int id = cidx[i];
    int rank = 0;
    for (int j = 0; j < m; ++j) {
        float vj = cval[j]; int ij = cidx[j];
        if (vj > v || (vj == v && ij < id)) ++rank;
    }
    if (rank < k) { perm[rank] = id; vals[rank] = v; }
}

__global__ void k_gru_deg(const float* __restrict__ x, const int* __restrict__ perm,
                          const float* __restrict__ vals, const float* __restrict__ W0,
                          const float* __restrict__ w_ih, const float* __restrict__ w_hh,
                          const float* __restrict__ b_ih, const float* __restrict__ b_hh,
                          unsigned short* __restrict__ WhT,
                          int degB, const int* __restrict__ ei, const float* __restrict__ ew,
                          unsigned long long* __restrict__ packed, int* __restrict__ eseq,
                          int e0, int e1, int ne) {
    __shared__ float sx[DIM], sh[DIM];
    int mi, di;
    if (pick_deg((int)blockIdx.x, degB, (int)gridDim.x, &mi, &di)) {
        int e = e0 + di * 128 + (int)threadIdx.x;
        if (e < e1) deg_edge(ei, ew, packed, eseq, ne, e);
        return;
    }
    int i = mi, c = threadIdx.x;
    sx[c] = x[(size_t)perm[i] * DIM + c] * tanhf(vals[i]);
    sh[c] = W0[i * DIM + c];
    __syncthreads();
    float gr = b_ih[c], gz = b_ih[DIM + c], gn = b_ih[2 * DIM + c];
    float hr = b_hh[c], hz = b_hh[DIM + c], hn = b_hh[2 * DIM + c];
    const float* wr = w_ih + (size_t)c * DIM;
    const float* wz = w_ih + (size_t)(DIM + c) * DIM;
    const float* wn = w_ih + (size_t)(2 * DIM + c) * DIM;
    const float* ur = w_hh + (size_t)c * DIM;
    const float* uz = w_hh + (size_t)(DIM + c) * DIM;
    const float* un = w_hh + (size_t)(2 * DIM + c) * DIM;
    for (int d = 0; d < DIM; ++d) {
        float xd = sx[d], hd = sh[d];
        gr += xd * wr[d]; gz += xd * wz[d]; gn += xd * wn[d];
        hr += hd * ur[d]; hz += hd * uz[d]; hn += hd * un[d];
    }
    float r = 1.0f / (1.0f + expf(-(gr + hr)));
    float z = 1.0f / (1.0f + expf(-(gz + hz)));
    float nn = tanhf(gn + r * hn);
    float wv = (1.0f - z) * nn + z * sh[c];
    WhT[(size_t)c * DIM + i] = (unsigned short)bf16rn(wv);
}

__global__ __launch_bounds__(256) void k_xw_deg(const float* __restrict__ x,
                                                const unsigned short* __restrict__ WhT,
                                                unsigned short* __restrict__ xwh, int n,
                                                int degB, const int* __restrict__ ei,
                                                const float* __restrict__ ew,
                                                unsigned long long* __restrict__ packed,
                                                int* __restrict__ eseq,
                                                int e0, int e1, int ne) {
    __shared__ unsigned short xs[64 * DIM];
    int mi, di;
    if (pick_deg((int)blockIdx.x, degB, (int)gridDim.x, &mi, &di)) {
        int e = e0 + di * 256 + (int)threadIdx.x;
        if (e < e1) deg_edge(ei, ew, packed, eseq, ne, e);
        return;
    }
    int nTr = (n + 63) / 64;
    int r0 = (mi % nTr) * 64;
    int c0 = (mi / nTr) * 64;
    int t = threadIdx.x;
    {
        int r = t >> 2;
        int row = r0 + r; if (row >= n) row = n - 1;
        const float4* xr = (const float4*)(x + (size_t)row * DIM);
#pragma unroll
        for (int j = 0; j < 4; ++j) {
            int g = (t & 3) + 4 * j;
            float4 lo = xr[g * 2], hi = xr[g * 2 + 1];
            uint4 o;
            o.x = pack2bf(lo.x, lo.y); o.y = pack2bf(lo.z, lo.w);
            o.z = pack2bf(hi.x, hi.y); o.w = pack2bf(hi.z, hi.w);
            *(uint4*)&xs[r * DIM + ((g ^ (r & 7)) << 3)] = o;
        }
    }
    __syncthreads();
    int wid = t >> 6, lane = t & 63;
    int lr = wid * 16 + (lane & 15);
    int kg = lane >> 4;
    int cA = lane & 15;
    f32x4 acc[4] = {{0.f,0.f,0.f,0.f},{0.f,0.f,0.f,0.f},{0.f,0.f,0.f,0.f},{0.f,0.f,0.f,0.f}};
    const bf16x8* wt = (const bf16x8*)WhT;
#pragma unroll
    for (int q = 0; q < 4; ++q) {
        bf16x8 a = *(const bf16x8*)&xs[lr * DIM + (((q * 4 + kg) ^ (lr & 7)) << 3)];
#pragma unroll
        for (int ct = 0; ct < 4; ++ct) {
            bf16x8 b = wt[(size_t)(c0 + ct * 16 + cA) * 16 + q * 4 + kg];
            acc[ct] = __builtin_amdgcn_mfma_f32_16x16x32_bf16(a, b, acc[ct], 0, 0, 0);
        }
    }
    int orow = r0 + wid * 16 + (lane >> 4) * 4;
#pragma unroll
    for (int reg = 0; reg < 4; ++reg) {
        int row = orow + reg;
        if (row < n) {
            unsigned short* dst = xwh + (size_t)row * DIM + c0 + cA;
#pragma unroll
            for (int ct = 0; ct < 4; ++ct)
                dst[ct * 16] = (unsigned short)bf16rn(acc[ct][reg]);
        }
    }
}

__global__ void k_dinv_scan1(const unsigned long long* __restrict__ packed,
                             float* __restrict__ dinv, int* __restrict__ cnt,
                             int* __restrict__ bsum, int n) {
    __shared__ int red[256];
    int b = blockIdx.x, t = threadIdx.x;
    int chunk = (n + SCAN_B - 1) / SCAN_B;
    int lo = b * chunk;
    int hi = lo + chunk; if (hi > n) hi = n;
    int s = 0;
    for (int i = lo + t; i < hi; i += 256) {
        unsigned long long pk = packed[i];
        float sumw = (float)((double)(pk & ((1ull << 40) - 1ull)) * (1.0 / 4294967296.0));
        dinv[i] = rsqrtf(1.0f + sumw);
        int c = (int)(pk >> 40);
        cnt[i] = c;
        s += c;
    }
    red[t] = s;
    __syncthreads();
    for (int off = 128; off > 0; off >>= 1) {
        if (t < off) red[t] += red[t + off];
        __syncthreads();
    }
    if (t == 0) bsum[b] = red[0];
}

__global__ void k_scan3f(const int* __restrict__ cnt, const int* __restrict__ bsum,
                         int* __restrict__ offs, int n) {
    __shared__ int sb[SCAN_B];
    __shared__ int red[256];
    int b = blockIdx.x, t = threadIdx.x;
    sb[t] = bsum[t];
    __syncthreads();
    for (int off = 1; off < SCAN_B; off <<= 1) {
        int v = (t >= off) ? sb[t - off] : 0;
        __syncthreads();
        sb[t] += v;
        __syncthreads();
    }
    int bbase = (b > 0) ? sb[b - 1] : 0;
    int total = sb[SCAN_B - 1];
    int chunk = (n + SCAN_B - 1) / SCAN_B;
    int lo = b * chunk;
    int hi = lo + chunk; if (hi > n) hi = n;
    int tchunk = (chunk + 255) / 256;
    int tlo = lo + t * tchunk;
    int thi = tlo + tchunk; if (thi > hi) thi = hi;
    int s = 0;
    for (int i = tlo; i < thi; ++i) s += cnt[i];
    red[t] = s;
    __syncthreads();
    for (int off = 1; off < 256; off <<= 1) {
        int v = (t >= off) ? red[t - off] : 0;
        __syncthreads();
        red[t] += v;
        __syncthreads();
    }
    int run = bbase + ((t > 0) ? red[t - 1] : 0);
    for (int i = tlo; i < thi; ++i) {
        offs[i] = run; run += cnt[i];
    }
    if (b == 0 && t == 0) offs[n] = total;
}

__global__ void k_fill(const int* __restrict__ ei, const float* __restrict__ ew,
                       const float* __restrict__ dinv, const int* __restrict__ offs,
                       const int* __restrict__ eseq, int2* __restrict__ edata, int ne) {
    int e = blockIdx.x * blockDim.x + threadIdx.x;
    if (e >= ne) return;
    int r = ei[e], c = ei[ne + e];
    float nrm = dinv[r] * ew[e] * dinv[c];
    int pos = offs[c] + eseq[e];
    edata[pos] = make_int2(r, __float_as_int(nrm));
}

// per-node gather + fused relu-linear head: 16 lanes/node, 8-deep load clustering
__global__ __launch_bounds__(256) void k_gather(const unsigned short* __restrict__ xwh,
        const float* __restrict__ dinv, const int* __restrict__ offs,
        const int2* __restrict__ edata, const float* __restrict__ w_lin,
        const float* __restrict__ b_lin, float* __restrict__ out, int n) {
    int gid = blockIdx.x * 256 + threadIdx.x;
    int c = gid >> 4, lane = gid & 15;
    if (c >= n) return;
    const uint4* xw4 = (const uint4*)xwh;
    float dd = dinv[c]; dd *= dd;
    float acc[8];
    {
        uint4 a = xw4[(size_t)c * 16 + lane];
        unsigned w[4] = {a.x, a.y, a.z, a.w};
#pragma unroll
        for (int q = 0; q < 4; ++q) {
            acc[2 * q]     = __uint_as_float(w[q] << 16) * dd;
            acc[2 * q + 1] = __uint_as_float(w[q] & 0xffff0000u) * dd;
        }
    }
    int start = offs[c], end = offs[c + 1];
    for (int base = start; base < end; base += 16) {
        int m = end - base; if (m > 16) m = 16;
        int2 ed = (base + lane < end) ? edata[base + lane] : make_int2(0, 0);
        for (int j0 = 0; j0 < m; j0 += 8) {
            uint4 v[8]; float nr[8];
#pragma unroll
            for (int jj = 0; jj < 8; ++jj) {
                int j = j0 + jj;
                int src = __shfl(ed.x, j & 15, 16);
                nr[jj] = (j < m) ? __int_as_float(__shfl(ed.y, j & 15, 16)) : 0.0f;
                v[jj] = xw4[(size_t)src * 16 + lane];
            }
#pragma unroll
            for (int jj = 0; jj < 8; ++jj) {
                unsigned w[4] = {v[jj].x, v[jj].y, v[jj].z, v[jj].w};
#pragma unroll
                for (int q = 0; q < 4; ++q) {
                    acc[2 * q]     += __uint_as_float(w[q] << 16) * nr[jj];
                    acc[2 * q + 1] += __uint_as_float(w[q] & 0xffff0000u) * nr[jj];
                }
            }
        }
    }
    float4 wla = ((const float4*)w_lin)[lane * 2];
    float4 wlb = ((const float4*)w_lin)[lane * 2 + 1];
    float r = fmaxf(acc[0], 0.0f) * wla.x + fmaxf(acc[1], 0.0f) * wla.y +
              fmaxf(acc[2], 0.0f) * wla.z + fmaxf(acc[3], 0.0f) * wla.w +
              fmaxf(acc[4], 0.0f) * wlb.x + fmaxf(acc[5], 0.0f) * wlb.y +
              fmaxf(acc[6], 0.0f) * wlb.z + fmaxf(acc[7], 0.0f) * wlb.w;
#pragma unroll
    for (int m = 8; m >= 1; m >>= 1) r += __shfl_xor(r, m, 16);
    if (lane == 0) out[c] = r + b_lin[0];
}

extern "C" void kernel_launch(void* const* d_in, const int* in_sizes, int n_in,
                              void* d_out, int out_size, void* d_ws, size_t ws_size,
                              hipStream_t stream) {
    const float* x     = (const float*)d_in[0];
    const int*   ei    = (const int*)d_in[1];
    const float* ew    = (const float*)d_in[2];
    const float* p     = (const float*)d_in[3];
    const float* W0    = (const float*)d_in[4];
    const float* w_ih  = (const float*)d_in[5];
    const float* w_hh  = (const float*)d_in[6];
    const float* b_ih  = (const float*)d_in[7];
    const float* b_hh  = (const float*)d_in[8];
    const float* w_lin = (const float*)d_in[9];
    const float* b_lin = (const float*)d_in[10];
    float* out = (float*)d_out;
    int n  = in_sizes[0] / DIM;
    int ne = in_sizes[2];
    (void)n_in; (void)out_size; (void)ws_size;

    char* base = (char*)d_ws;
    size_t o = 0;
    auto alloc = [&](size_t b) { size_t r = o; o += (b + 255) & ~(size_t)255; return r; };
    float*    score   = (float*)(base + alloc((size_t)n * 4));
    unsigned* hist    = (unsigned*)(base + alloc(HSIZE * 4));
    unsigned* counter = (unsigned*)(base + alloc(256));
    unsigned* binfo   = (unsigned*)(base + alloc(256));
    float*    cval    = (float*)(base + alloc((size_t)CAP * 4));
    int*      cidx    = (int*)(base + alloc((size_t)CAP * 4));
    int*      perm    = (int*)(base + alloc(TOPK * 4));
    float*    vals    = (float*)(base + alloc(TOPK * 4));
    float*    pinv    = (float*)(base + alloc(256));
    unsigned short* WhT = (unsigned short*)(base + alloc(DIM * DIM * 2));
    float*    dinv    = (float*)(base + alloc((size_t)n * 4));
    int*      cnt     = (int*)(base + alloc((size_t)n * 4));
    int*      offs    = (int*)(base + alloc((size_t)(n + 1) * 4));
    unsigned long long* packed = (unsigned long long*)(base + alloc((size_t)n * 8));
    int*      eseq    = (int*)(base + alloc((size_t)ne * 4));
    int*      bsum    = (int*)(base + alloc((SCAN_B + 1) * 4));
    int2*     edata   = (int2*)(base + alloc((size_t)ne * 8));
    unsigned short* xwh = (unsigned short*)(base + alloc((size_t)n * DIM * 2));

    // score kernel hides first s0 edges; rest handled by mega phases (or fallback)
    int s0 = 450000 < ne ? 450000 : ne;
    int rem = ne - s0;
    int eA = s0;
    int eB = s0 + (int)((long long)rem * 20 / 100);
    int eC = s0 + (int)((long long)rem * 35 / 100);
    int eD = s0 + (int)((long long)rem * 50 / 100);
    int eE = s0 + (int)((long long)rem * 70 / 100);

    int sl_blocks = (s0 + 255) / 256;
    int scoreMB = (n * 16 + 255) / 256;

    k_pnorm_zero<<<1 + (n + 1023) / 1024, 128, 0, stream>>>(p, pinv, packed, hist, counter, n);
    k_score_deg<<<scoreMB + sl_blocks, 256, 0, stream>>>(
        x, p, pinv, score, hist, n, sl_blocks, ei, ew, packed, eseq, 0, s0, ne);

    void* margs[] = {
        (void*)&x, (void*)&ei, (void*)&ew, (void*)&hist, (void*)&binfo, (void*)&score,
        (void*)&counter, (void*)&cval, (void*)&cidx, (void*)&perm, (void*)&vals,
        (void*)&W0, (void*)&w_ih, (void*)&w_hh, (void*)&b_ih, (void*)&b_hh,
        (void*)&WhT, (void*)&xwh, (void*)&packed, (void*)&eseq, (void*)&dinv,
        (void*)&cnt, (void*)&bsum, (void*)&offs, (void*)&edata,
        (void*)&n, (void*)&ne, (void*)&eA, (void*)&eB, (void*)&eC, (void*)&eD, (void*)&eE };
    hipError_t cerr = hipLaunchCooperativeKernel((void*)k_mega, dim3(MEGA_B), dim3(256),
                                                 margs, 0, stream);
    if (cerr != hipSuccess) {
        (void)hipGetLastError();   // clear sticky error; use proven multi-kernel path
        int r2 = ne - s0;
        int fA = s0, fB = s0 + (int)((long long)r2 * 15 / 100);
        int fC = s0 + (int)((long long)r2 * 35 / 100);
        int fD = s0 + (int)((long long)r2 * 55 / 100);
        int fE = s0 + (int)((long long)r2 * 75 / 100);
        int colMB = (n + 255) / 256;
        int xwMB  = ((n + 63) / 64) * 2;
        int bFB = (fB - fA + 1023) / 1024;
        int bCol = (fC - fB + 255) / 256;
        int bRank = (fD - fC + 255) / 256;
        int bGru = (fE - fD + 127) / 128;
        int bXw = (ne - fE + 255) / 256;
        k_findbin_deg<<<1 + bFB, 1024, 0, stream>>>(
            hist, binfo, TOPK, ei, ew, packed, eseq, fA, fB, ne);
        k_collect_deg<<<colMB + bCol, 256, 0, stream>>>(
            score, binfo, counter, cval, cidx, n, bCol, ei, ew, packed, eseq, fB, fC, ne);
        k_rank_deg<<<(CAP / 256) + bRank, 256, 0, stream>>>(
            cval, cidx, counter, perm, vals, TOPK, bRank, ei, ew, packed, eseq, fC, fD, ne);
        k_gru_deg<<<DIM + bGru, 128, 0, stream>>>(
            x, perm, vals, W0, w_ih, w_hh, b_ih, b_hh, WhT, bGru, ei, ew, packed, eseq,
            fD, fE, ne);
        k_xw_deg<<<xwMB + bXw, 256, 0, stream>>>(
            x, WhT, xwh, n, bXw, ei, ew, packed, eseq, fE, ne, ne);
        k_dinv_scan1<<<SCAN_B, 256, 0, stream>>>(packed, dinv, cnt, bsum, n);
        k_scan3f<<<SCAN_B, 256, 0, stream>>>(cnt, bsum, offs, n);
        k_fill<<<(ne + 255) / 256, 256, 0, stream>>>(ei, ew, dinv, offs, eseq, edata, ne);
    }

    long long g_threads = (long long)n * 16;
    k_gather<<<(int)((g_threads + 255) / 256), 256, 0, stream>>>(
        xwh, dinv, offs, edata, w_lin, b_lin, out, n);
}

// Round 14
// 257.392 us; speedup vs baseline: 2.6393x; 2.6393x over previous
//
#include <hip/hip_runtime.h>
#include <hip/hip_bf16.h>
#include <math.h>

#define DIM 128
#define TOPK 128
#define CAP 4096
#define SCAN_B 256
#define HSIZE 16384
#define HSHIFT 18          // f2k >> 18 -> 14-bit bin
#define HMUL 10937u        // odd -> bijective mod 2^14

typedef __attribute__((ext_vector_type(8))) short bf16x8;
typedef __attribute__((ext_vector_type(4))) float f32x4;

__device__ __forceinline__ unsigned f2k(float f) {
    unsigned b = __float_as_uint(f);
    return (b & 0x80000000u) ? ~b : (b | 0x80000000u);
}

__device__ __forceinline__ unsigned hidx(unsigned bin) {
    return (bin * HMUL) & (HSIZE - 1u);
}

// round-to-nearest-even bf16 (as high 16 bits of fp32)
__device__ __forceinline__ unsigned bf16rn(float v) {
    unsigned u = __float_as_uint(v);
    u += 0x7fffu + ((u >> 16) & 1u);
    return u >> 16;
}

__device__ __forceinline__ unsigned pack2bf(float lo, float hi) {
    return (bf16rn(hi) << 16) | bf16rn(lo);
}

// one u64 atomic per edge: [63:40] count, [39:0] fixed-point weight sum (2^-32).
__device__ __forceinline__ void deg_edge(const int* __restrict__ ei, const float* __restrict__ ew,
                                         unsigned long long* __restrict__ packed,
                                         int* __restrict__ eseq, int ne, int e) {
    int c = ei[ne + e];
    float w = ew[e];
    unsigned long long fx = (unsigned long long)((double)w * 4294967296.0);
    unsigned long long old = atomicAdd(&packed[c], (1ull << 40) | fx);
    eseq[e] = (int)(old >> 40);
}

// Bresenham interleave of degB deg-blocks among T total blocks.
__device__ __forceinline__ bool pick_deg(int bid, int degB, int T, int* mi, int* di) {
    long long a = (long long)bid * degB;
    int before = (int)(a / T);
    if ((int)((a + degB) / T) > before) { *di = before; return true; }
    *mi = bid - before;
    return false;
}

// block 0: ||p|| ; other blocks: zero packed + hist + counter
__global__ void k_pnorm_zero(const float* __restrict__ p, float* __restrict__ pinv,
                             unsigned long long* __restrict__ packed,
                             unsigned* __restrict__ hist, unsigned* __restrict__ counter, int n) {
    if (blockIdx.x == 0) {
        __shared__ float s[DIM];
        int t = threadIdx.x;
        float v = p[t];
        s[t] = v * v;
        __syncthreads();
        for (int off = 64; off > 0; off >>= 1) {
            if (t < off) s[t] += s[t + off];
            __syncthreads();
        }
        if (t == 0) pinv[0] = 1.0f / sqrtf(s[0]);
    } else {
        int base = ((int)blockIdx.x - 1) * 1024 + (int)threadIdx.x;
        if (blockIdx.x == 1 && threadIdx.x == 0) counter[0] = 0u;
#pragma unroll
        for (int j = 0; j < 8; ++j) {
            int i = base + j * 128;
            if (i < n) packed[i] = 0ull;
            if (i < HSIZE) hist[i] = 0u;
        }
    }
}

// 16 lanes per node (2x float4 each): score + spread-hist bin, + deg slice
__global__ void k_score_deg(const float* __restrict__ x, const float* __restrict__ p,
                            const float* __restrict__ pinv, float* __restrict__ score,
                            unsigned* __restrict__ hist, int n,
                            int degB, const int* __restrict__ ei, const float* __restrict__ ew,
                            unsigned long long* __restrict__ packed, int* __restrict__ eseq,
                            int e0, int e1, int ne) {
    int mi, di;
    if (pick_deg((int)blockIdx.x, degB, (int)gridDim.x, &mi, &di)) {
        int e = e0 + di * 256 + (int)threadIdx.x;
        if (e < e1) deg_edge(ei, ew, packed, eseq, ne, e);
        return;
    }
    int gid = mi * 256 + (int)threadIdx.x;
    int node = gid >> 4, lane = gid & 15;
    if (node >= n) return;
    const float4* xr = (const float4*)(x) + (size_t)node * 32;
    const float4* p4 = (const float4*)p;
    float4 a0 = xr[lane * 2], a1 = xr[lane * 2 + 1];
    float4 b0 = p4[lane * 2], b1 = p4[lane * 2 + 1];
    float acc = a0.x * b0.x + a0.y * b0.y + a0.z * b0.z + a0.w * b0.w +
                a1.x * b1.x + a1.y * b1.y + a1.z * b1.z + a1.w * b1.w;
#pragma unroll
    for (int m = 8; m >= 1; m >>= 1) acc += __shfl_xor(acc, m, 16);
    if (lane == 0) {
        float s = acc * pinv[0];
        score[node] = s;
        atomicAdd(&hist[hidx(f2k(s) >> HSHIFT)], 1u);
    }
}

// block 0: find threshold bin (16 bins/thread); other blocks: deg slice
__global__ void k_findbin_deg(const unsigned* __restrict__ hist, unsigned* __restrict__ binfo, int k,
                              const int* __restrict__ ei, const float* __restrict__ ew,
                              unsigned long long* __restrict__ packed, int* __restrict__ eseq,
                              int e0, int e1, int ne) {
    if (blockIdx.x > 0) {
        int e = e0 + ((int)blockIdx.x - 1) * 1024 + (int)threadIdx.x;
        if (e < e1) deg_edge(ei, ew, packed, eseq, ne, e);
        return;
    }
    __shared__ unsigned csum[1024];
    int t = threadIdx.x;
    unsigned hv[16];
    unsigned s = 0;
#pragma unroll
    for (int j = 0; j < 16; ++j) {
        hv[j] = hist[hidx(t * 16 + j)];
        s += hv[j];
    }
    csum[t] = s;
    __syncthreads();
    for (int off = 1; off < 1024; off <<= 1) {
        unsigned v = (t + off < 1024) ? csum[t + off] : 0u;
        __syncthreads();
        csum[t] += v;
        __syncthreads();
    }
    unsigned run = (t + 1 < 1024) ? csum[t + 1] : 0u;
#pragma unroll
    for (int j = 15; j >= 0; --j) {
        unsigned h = hv[j];
        if (h > 0u && run < (unsigned)k && run + h >= (unsigned)k) {
            binfo[0] = (unsigned)(t * 16 + j);
            binfo[1] = run;
        }
        run += h;
    }
}

__global__ void k_collect_deg(const float* __restrict__ score, const unsigned* __restrict__ binfo,
                              unsigned* __restrict__ counter, float* __restrict__ cval,
                              int* __restrict__ cidx, int n,
                              int degB, const int* __restrict__ ei, const float* __restrict__ ew,
                              unsigned long long* __restrict__ packed, int* __restrict__ eseq,
                              int e0, int e1, int ne) {
    int mi, di;
    if (pick_deg((int)blockIdx.x, degB, (int)gridDim.x, &mi, &di)) {
        int e = e0 + di * 256 + (int)threadIdx.x;
        if (e < e1) deg_edge(ei, ew, packed, eseq, ne, e);
        return;
    }
    int i = mi * 256 + (int)threadIdx.x;
    if (i >= n) return;
    float s = score[i];
    if ((f2k(s) >> HSHIFT) >= binfo[0]) {
        unsigned pos = atomicAdd(counter, 1u);
        if (pos < CAP) { cval[pos] = s; cidx[pos] = i; }
    }
}

// rank-based exact top-k (matches jax.lax.top_k: desc, lower index wins ties)
__global__ void k_rank_deg(const float* __restrict__ cval, const int* __restrict__ cidx,
                           const unsigned* __restrict__ counter, int* __restrict__ perm,
                           float* __restrict__ vals, int k,
                           int degB, const int* __restrict__ ei, const float* __restrict__ ew,
                           unsigned long long* __restrict__ packed, int* __restrict__ eseq,
                           int e0, int e1, int ne) {
    int mi, di;
    if (pick_deg((int)blockIdx.x, degB, (int)gridDim.x, &mi, &di)) {
        int e = e0 + di * 256 + (int)threadIdx.x;
        if (e < e1) deg_edge(ei, ew, packed, eseq, ne, e);
        return;
    }
    int i = mi * 256 + (int)threadIdx.x;
    unsigned cnt = counter[0];
    int m = (cnt < (unsigned)CAP) ? (int)cnt : CAP;
    if (i >= m) return;
    float v = cval[i]; int id = cidx[i];
    int rank = 0;
    for (int j = 0; j < m; ++j) {
        float vj = cval[j]; int ij = cidx[j];
        if (vj > v || (vj == v && ij < id)) ++rank;
    }
    if (rank < k) { perm[rank] = id; vals[rank] = v; }
}

// GRU with fused x_tilde + deg slice; writes W TRANSPOSED in bf16 ([c][i], 32KB)
__global__ void k_gru_deg(const float* __restrict__ x, const int* __restrict__ perm,
                          const float* __restrict__ vals, const float* __restrict__ W0,
                          const float* __restrict__ w_ih, const float* __restrict__ w_hh,
                          const float* __restrict__ b_ih, const float* __restrict__ b_hh,
                          unsigned short* __restrict__ WhT,
                          int degB, const int* __restrict__ ei, const float* __restrict__ ew,
                          unsigned long long* __restrict__ packed, int* __restrict__ eseq,
                          int e0, int e1, int ne) {
    __shared__ float sx[DIM], sh[DIM];
    int mi, di;
    if (pick_deg((int)blockIdx.x, degB, (int)gridDim.x, &mi, &di)) {
        int e = e0 + di * 128 + (int)threadIdx.x;
        if (e < e1) deg_edge(ei, ew, packed, eseq, ne, e);
        return;
    }
    int i = mi, c = threadIdx.x;
    sx[c] = x[(size_t)perm[i] * DIM + c] * tanhf(vals[i]);
    sh[c] = W0[i * DIM + c];
    __syncthreads();
    float gr = b_ih[c], gz = b_ih[DIM + c], gn = b_ih[2 * DIM + c];
    float hr = b_hh[c], hz = b_hh[DIM + c], hn = b_hh[2 * DIM + c];
    const float* wr = w_ih + (size_t)c * DIM;
    const float* wz = w_ih + (size_t)(DIM + c) * DIM;
    const float* wn = w_ih + (size_t)(2 * DIM + c) * DIM;
    const float* ur = w_hh + (size_t)c * DIM;
    const float* uz = w_hh + (size_t)(DIM + c) * DIM;
    const float* un = w_hh + (size_t)(2 * DIM + c) * DIM;
    for (int d = 0; d < DIM; ++d) {
        float xd = sx[d], hd = sh[d];
        gr += xd * wr[d]; gz += xd * wz[d]; gn += xd * wn[d];
        hr += hd * ur[d]; hz += hd * uz[d]; hn += hd * un[d];
    }
    float r = 1.0f / (1.0f + expf(-(gr + hr)));
    float z = 1.0f / (1.0f + expf(-(gz + hz)));
    float nn = tanhf(gn + r * hn);
    float wv = (1.0f - z) * nn + z * sh[c];
    WhT[(size_t)c * DIM + i] = (unsigned short)bf16rn(wv);   // transposed bf16
}

// xw = x @ W -> bf16 via MFMA 16x16x32. 64x64 tile, 4 waves, 16KB LDS (bf16 x-tile,
// granule-XOR swizzle). W^T bf16 read from global (32KB, L2-resident).
__global__ __launch_bounds__(256) void k_xw_deg(const float* __restrict__ x,
                                                const unsigned short* __restrict__ WhT,
                                                unsigned short* __restrict__ xwh, int n,
                                                int degB, const int* __restrict__ ei,
                                                const float* __restrict__ ew,
                                                unsigned long long* __restrict__ packed,
                                                int* __restrict__ eseq,
                                                int e0, int e1, int ne) {
    __shared__ unsigned short xs[64 * DIM];   // 16KB: [r][k] bf16, granule g^=(r&7)
    int mi, di;
    if (pick_deg((int)blockIdx.x, degB, (int)gridDim.x, &mi, &di)) {
        int e = e0 + di * 256 + (int)threadIdx.x;
        if (e < e1) deg_edge(ei, ew, packed, eseq, ne, e);
        return;
    }
    int nTr = (n + 63) / 64;
    int r0 = (mi % nTr) * 64;
    int c0 = (mi / nTr) * 64;
    int t = threadIdx.x;
    {
        int r = t >> 2;
        int row = r0 + r; if (row >= n) row = n - 1;
        const float4* xr = (const float4*)(x + (size_t)row * DIM);
#pragma unroll
        for (int j = 0; j < 4; ++j) {
            int g = (t & 3) + 4 * j;
            float4 lo = xr[g * 2];
            float4 hi = xr[g * 2 + 1];
            uint4 o;
            o.x = pack2bf(lo.x, lo.y);
            o.y = pack2bf(lo.z, lo.w);
            o.z = pack2bf(hi.x, hi.y);
            o.w = pack2bf(hi.z, hi.w);
            *(uint4*)&xs[r * DIM + ((g ^ (r & 7)) << 3)] = o;
        }
    }
    __syncthreads();
    int wid = t >> 6, lane = t & 63;
    int lr = wid * 16 + (lane & 15);
    int kg = lane >> 4;
    int cA = lane & 15;
    f32x4 acc[4] = {{0.f,0.f,0.f,0.f},{0.f,0.f,0.f,0.f},{0.f,0.f,0.f,0.f},{0.f,0.f,0.f,0.f}};
    const bf16x8* wt = (const bf16x8*)WhT;
#pragma unroll
    for (int q = 0; q < 4; ++q) {
        bf16x8 a = *(const bf16x8*)&xs[lr * DIM + (((q * 4 + kg) ^ (lr & 7)) << 3)];
#pragma unroll
        for (int ct = 0; ct < 4; ++ct) {
            bf16x8 b = wt[(size_t)(c0 + ct * 16 + cA) * 16 + q * 4 + kg];
            acc[ct] = __builtin_amdgcn_mfma_f32_16x16x32_bf16(a, b, acc[ct], 0, 0, 0);
        }
    }
    int orow = r0 + wid * 16 + (lane >> 4) * 4;
#pragma unroll
    for (int reg = 0; reg < 4; ++reg) {
        int row = orow + reg;
        if (row < n) {
            unsigned short* dst = xwh + (size_t)row * DIM + c0 + cA;
#pragma unroll
            for (int ct = 0; ct < 4; ++ct)
                dst[ct * 16] = (unsigned short)bf16rn(acc[ct][reg]);
        }
    }
}

// fused: unpack packed -> dinv/cnt AND per-block partial sums for scan
__global__ void k_dinv_scan1(const unsigned long long* __restrict__ packed,
                             float* __restrict__ dinv, int* __restrict__ cnt,
                             int* __restrict__ bsum, int n) {
    __shared__ int red[256];
    int b = blockIdx.x, t = threadIdx.x;
    int chunk = (n + SCAN_B - 1) / SCAN_B;
    int lo = b * chunk;
    int hi = lo + chunk; if (hi > n) hi = n;
    int s = 0;
    for (int i = lo + t; i < hi; i += 256) {
        unsigned long long pk = packed[i];
        float sumw = (float)((double)(pk & ((1ull << 40) - 1ull)) * (1.0 / 4294967296.0));
        dinv[i] = rsqrtf(1.0f + sumw);
        int c = (int)(pk >> 40);
        cnt[i] = c;
        s += c;
    }
    red[t] = s;
    __syncthreads();
    for (int off = 128; off > 0; off >>= 1) {
        if (t < off) red[t] += red[t + off];
        __syncthreads();
    }
    if (t == 0) bsum[b] = red[0];
}

// fused scan2+scan3: each block locally scans bsum, then writes its offs chunk
__global__ void k_scan3f(const int* __restrict__ cnt, const int* __restrict__ bsum,
                         int* __restrict__ offs, int n) {
    __shared__ int sb[SCAN_B];
    __shared__ int red[256];
    int b = blockIdx.x, t = threadIdx.x;
    sb[t] = bsum[t];
    __syncthreads();
    for (int off = 1; off < SCAN_B; off <<= 1) {
        int v = (t >= off) ? sb[t - off] : 0;
        __syncthreads();
        sb[t] += v;
        __syncthreads();
    }
    int bbase = (b > 0) ? sb[b - 1] : 0;
    int total = sb[SCAN_B - 1];
    int chunk = (n + SCAN_B - 1) / SCAN_B;
    int lo = b * chunk;
    int hi = lo + chunk; if (hi > n) hi = n;
    int tchunk = (chunk + 255) / 256;
    int tlo = lo + t * tchunk;
    int thi = tlo + tchunk; if (thi > hi) thi = hi;
    int s = 0;
    for (int i = tlo; i < thi; ++i) s += cnt[i];
    red[t] = s;
    __syncthreads();
    for (int off = 1; off < 256; off <<= 1) {
        int v = (t >= off) ? red[t - off] : 0;
        __syncthreads();
        red[t] += v;
        __syncthreads();
    }
    int run = bbase + ((t > 0) ? red[t - 1] : 0);
    for (int i = tlo; i < thi; ++i) {
        offs[i] = run; run += cnt[i];
    }
    if (b == 0 && t == 0) offs[n] = total;
}

// bucket edges by destination, atomic-free: pos = offs[c] + eseq[e]
__global__ void k_fill(const int* __restrict__ ei, const float* __restrict__ ew,
                       const float* __restrict__ dinv, const int* __restrict__ offs,
                       const int* __restrict__ eseq, int2* __restrict__ edata, int ne) {
    int e = blockIdx.x * blockDim.x + threadIdx.x;
    if (e >= ne) return;
    int r = ei[e], c = ei[ne + e];
    float nrm = dinv[r] * ew[e] * dinv[c];
    int pos = offs[c] + eseq[e];
    edata[pos] = make_int2(r, __float_as_int(nrm));
}

// per-node gather + fused relu-linear head: 16 lanes per node, 8 bf16 (16B) each.
// 8-deep load clustering for memory-level parallelism.
__global__ __launch_bounds__(256) void k_gather(const unsigned short* __restrict__ xwh,
        const float* __restrict__ dinv, const int* __restrict__ offs,
        const int2* __restrict__ edata, const float* __restrict__ w_lin,
        const float* __restrict__ b_lin, float* __restrict__ out, int n) {
    int gid = blockIdx.x * 256 + threadIdx.x;
    int c = gid >> 4, lane = gid & 15;
    if (c >= n) return;
    const uint4* xw4 = (const uint4*)xwh;
    float dd = dinv[c]; dd *= dd;
    float acc[8];
    {
        uint4 a = xw4[(size_t)c * 16 + lane];
        unsigned w[4] = {a.x, a.y, a.z, a.w};
#pragma unroll
        for (int q = 0; q < 4; ++q) {
            acc[2 * q]     = __uint_as_float(w[q] << 16) * dd;
            acc[2 * q + 1] = __uint_as_float(w[q] & 0xffff0000u) * dd;
        }
    }
    int start = offs[c], end = offs[c + 1];
    for (int base = start; base < end; base += 16) {
        int m = end - base; if (m > 16) m = 16;
        int2 ed = (base + lane < end) ? edata[base + lane] : make_int2(0, 0);
        for (int j0 = 0; j0 < m; j0 += 8) {
            uint4 v[8]; float nr[8];
#pragma unroll
            for (int jj = 0; jj < 8; ++jj) {
                int j = j0 + jj;
                int src = __shfl(ed.x, j & 15, 16);
                nr[jj] = (j < m) ? __int_as_float(__shfl(ed.y, j & 15, 16)) : 0.0f;
                v[jj] = xw4[(size_t)src * 16 + lane];
            }
#pragma unroll
            for (int jj = 0; jj < 8; ++jj) {
                unsigned w[4] = {v[jj].x, v[jj].y, v[jj].z, v[jj].w};
#pragma unroll
                for (int q = 0; q < 4; ++q) {
                    acc[2 * q]     += __uint_as_float(w[q] << 16) * nr[jj];
                    acc[2 * q + 1] += __uint_as_float(w[q] & 0xffff0000u) * nr[jj];
                }
            }
        }
    }
    float4 wla = ((const float4*)w_lin)[lane * 2];
    float4 wlb = ((const float4*)w_lin)[lane * 2 + 1];
    float r = fmaxf(acc[0], 0.0f) * wla.x + fmaxf(acc[1], 0.0f) * wla.y +
              fmaxf(acc[2], 0.0f) * wla.z + fmaxf(acc[3], 0.0f) * wla.w +
              fmaxf(acc[4], 0.0f) * wlb.x + fmaxf(acc[5], 0.0f) * wlb.y +
              fmaxf(acc[6], 0.0f) * wlb.z + fmaxf(acc[7], 0.0f) * wlb.w;
#pragma unroll
    for (int m = 8; m >= 1; m >>= 1) r += __shfl_xor(r, m, 16);
    if (lane == 0) out[c] = r + b_lin[0];
}

extern "C" void kernel_launch(void* const* d_in, const int* in_sizes, int n_in,
                              void* d_out, int out_size, void* d_ws, size_t ws_size,
                              hipStream_t stream) {
    const float* x     = (const float*)d_in[0];
    const int*   ei    = (const int*)d_in[1];
    const float* ew    = (const float*)d_in[2];
    const float* p     = (const float*)d_in[3];
    const float* W0    = (const float*)d_in[4];
    const float* w_ih  = (const float*)d_in[5];
    const float* w_hh  = (const float*)d_in[6];
    const float* b_ih  = (const float*)d_in[7];
    const float* b_hh  = (const float*)d_in[8];
    const float* w_lin = (const float*)d_in[9];
    const float* b_lin = (const float*)d_in[10];
    float* out = (float*)d_out;
    int n  = in_sizes[0] / DIM;
    int ne = in_sizes[2];
    (void)n_in; (void)out_size; (void)ws_size;

    char* base = (char*)d_ws;
    size_t o = 0;
    auto alloc = [&](size_t b) { size_t r = o; o += (b + 255) & ~(size_t)255; return r; };
    float*    score   = (float*)(base + alloc((size_t)n * 4));
    unsigned* hist    = (unsigned*)(base + alloc(HSIZE * 4));
    unsigned* counter = (unsigned*)(base + alloc(256));
    unsigned* binfo   = (unsigned*)(base + alloc(256));
    float*    cval    = (float*)(base + alloc((size_t)CAP * 4));
    int*      cidx    = (int*)(base + alloc((size_t)CAP * 4));
    int*      perm    = (int*)(base + alloc(TOPK * 4));
    float*    vals    = (float*)(base + alloc(TOPK * 4));
    float*    pinv    = (float*)(base + alloc(256));
    unsigned short* WhT = (unsigned short*)(base + alloc(DIM * DIM * 2));
    float*    dinv    = (float*)(base + alloc((size_t)n * 4));
    int*      cnt     = (int*)(base + alloc((size_t)n * 4));
    int*      offs    = (int*)(base + alloc((size_t)(n + 1) * 4));
    unsigned long long* packed = (unsigned long long*)(base + alloc((size_t)n * 8));
    int*      eseq    = (int*)(base + alloc((size_t)ne * 4));
    int*      bsum    = (int*)(base + alloc((SCAN_B + 1) * 4));
    int2*     edata   = (int2*)(base + alloc((size_t)ne * 8));
    unsigned short* xwh = (unsigned short*)(base + alloc((size_t)n * DIM * 2));

    // edge-slice assignment: hide deg atomics under independent kernels
    struct Slice { int e0, e1, blocks; };
    int cur = 0;
    auto take = [&](int want, int bs) {
        Slice s; s.e0 = cur;
        int t = want; if (cur + t > ne) t = ne - cur;
        s.e1 = cur + t; cur = s.e1;
        s.blocks = (t + bs - 1) / bs;
        return s;
    };
    Slice sl_score = take(250000, 256);
    Slice sl_fb    = take(150000, 1024);
    Slice sl_col   = take(250000, 256);
    Slice sl_rank  = take(250000, 256);
    Slice sl_gru   = take(300000, 128);
    Slice sl_xw    = take(ne, 256);        // remainder (~400k)

    int scoreMB = (n * 16 + 255) / 256;
    int colMB   = (n + 255) / 256;
    int xwMB    = ((n + 63) / 64) * 2;

    k_pnorm_zero<<<1 + (n + 1023) / 1024, 128, 0, stream>>>(p, pinv, packed, hist, counter, n);
    k_score_deg<<<scoreMB + sl_score.blocks, 256, 0, stream>>>(
        x, p, pinv, score, hist, n, sl_score.blocks, ei, ew, packed, eseq,
        sl_score.e0, sl_score.e1, ne);
    k_findbin_deg<<<1 + sl_fb.blocks, 1024, 0, stream>>>(
        hist, binfo, TOPK, ei, ew, packed, eseq, sl_fb.e0, sl_fb.e1, ne);
    k_collect_deg<<<colMB + sl_col.blocks, 256, 0, stream>>>(
        score, binfo, counter, cval, cidx, n, sl_col.blocks, ei, ew, packed, eseq,
        sl_col.e0, sl_col.e1, ne);
    k_rank_deg<<<(CAP / 256) + sl_rank.blocks, 256, 0, stream>>>(
        cval, cidx, counter, perm, vals, TOPK, sl_rank.blocks, ei, ew, packed, eseq,
        sl_rank.e0, sl_rank.e1, ne);
    k_gru_deg<<<DIM + sl_gru.blocks, 128, 0, stream>>>(
        x, perm, vals, W0, w_ih, w_hh, b_ih, b_hh, WhT, sl_gru.blocks, ei, ew, packed, eseq,
        sl_gru.e0, sl_gru.e1, ne);
    k_xw_deg<<<xwMB + sl_xw.blocks, 256, 0, stream>>>(
        x, WhT, xwh, n, sl_xw.blocks, ei, ew, packed, eseq, sl_xw.e0, sl_xw.e1, ne);
    k_dinv_scan1<<<SCAN_B, 256, 0, stream>>>(packed, dinv, cnt, bsum, n);
    k_scan3f<<<SCAN_B, 256, 0, stream>>>(cnt, bsum, offs, n);
    k_fill<<<(ne + 255) / 256, 256, 0, stream>>>(ei, ew, dinv, offs, eseq, edata, ne);
    long long g_threads = (long long)n * 16;
    k_gather<<<(int)((g_threads + 255) / 256), 256, 0, stream>>>(
        xwh, dinv, offs, edata, w_lin, b_lin, out, n);
}

// Round 15
// 241.633 us; speedup vs baseline: 2.8115x; 1.0652x over previous
//
#include <hip/hip_runtime.h>
#include <hip/hip_bf16.h>
#include <math.h>

#define DIM 128
#define TOPK 128
#define CAP 4096
#define SCAN_B 256
#define HSIZE 16384
#define HSHIFT 18          // f2k >> 18 -> 14-bit bin
#define HMUL 10937u        // odd -> bijective mod 2^14

typedef __attribute__((ext_vector_type(8))) short bf16x8;
typedef __attribute__((ext_vector_type(4))) float f32x4;

__device__ __forceinline__ unsigned f2k(float f) {
    unsigned b = __float_as_uint(f);
    return (b & 0x80000000u) ? ~b : (b | 0x80000000u);
}

__device__ __forceinline__ unsigned hidx(unsigned bin) {
    return (bin * HMUL) & (HSIZE - 1u);
}

// round-to-nearest-even bf16 (as high 16 bits of fp32)
__device__ __forceinline__ unsigned bf16rn(float v) {
    unsigned u = __float_as_uint(v);
    u += 0x7fffu + ((u >> 16) & 1u);
    return u >> 16;
}

__device__ __forceinline__ unsigned pack2bf(float lo, float hi) {
    return (bf16rn(hi) << 16) | bf16rn(lo);
}

// one u64 atomic per edge: [63:40] count, [39:0] fixed-point weight sum (2^-32).
__device__ __forceinline__ void deg_edge(const int* __restrict__ ei, const float* __restrict__ ew,
                                         unsigned long long* __restrict__ packed,
                                         unsigned short* __restrict__ eseq, int ne, int e) {
    int c = ei[ne + e];
    float w = ew[e];
    unsigned long long fx = (unsigned long long)((double)w * 4294967296.0);
    unsigned long long old = atomicAdd(&packed[c], (1ull << 40) | fx);
    eseq[e] = (unsigned short)(old >> 40);
}

// Bresenham interleave of degB deg-blocks among T total blocks.
__device__ __forceinline__ bool pick_deg(int bid, int degB, int T, int* mi, int* di) {
    long long a = (long long)bid * degB;
    int before = (int)(a / T);
    if ((int)((a + degB) / T) > before) { *di = before; return true; }
    *mi = bid - before;
    return false;
}

// 16 lanes per node (2x float4 each): UNSCALED score + spread-hist bin, + deg slice
__global__ void k_score_deg(const float* __restrict__ x, const float* __restrict__ p,
                            float* __restrict__ score,
                            unsigned* __restrict__ hist, int n,
                            int degB, const int* __restrict__ ei, const float* __restrict__ ew,
                            unsigned long long* __restrict__ packed,
                            unsigned short* __restrict__ eseq,
                            int e0, int e1, int ne) {
    int mi, di;
    if (pick_deg((int)blockIdx.x, degB, (int)gridDim.x, &mi, &di)) {
        int e = e0 + di * 256 + (int)threadIdx.x;
        if (e < e1) deg_edge(ei, ew, packed, eseq, ne, e);
        return;
    }
    int gid = mi * 256 + (int)threadIdx.x;
    int node = gid >> 4, lane = gid & 15;
    if (node >= n) return;
    const float4* xr = (const float4*)(x) + (size_t)node * 32;
    const float4* p4 = (const float4*)p;
    float4 a0 = xr[lane * 2], a1 = xr[lane * 2 + 1];
    float4 b0 = p4[lane * 2], b1 = p4[lane * 2 + 1];
    float acc = a0.x * b0.x + a0.y * b0.y + a0.z * b0.z + a0.w * b0.w +
                a1.x * b1.x + a1.y * b1.y + a1.z * b1.z + a1.w * b1.w;
#pragma unroll
    for (int m = 8; m >= 1; m >>= 1) acc += __shfl_xor(acc, m, 16);
    if (lane == 0) {
        score[node] = acc;                     // raw dot; ordering is scale-invariant
        atomicAdd(&hist[hidx(f2k(acc) >> HSHIFT)], 1u);
    }
}

// block 0: find threshold bin (16 bins/thread) + compute pinv; other blocks: deg slice
__global__ void k_findbin_deg(const unsigned* __restrict__ hist, unsigned* __restrict__ binfo,
                              int k, const float* __restrict__ p, float* __restrict__ pinv,
                              const int* __restrict__ ei, const float* __restrict__ ew,
                              unsigned long long* __restrict__ packed,
                              unsigned short* __restrict__ eseq,
                              int e0, int e1, int ne) {
    if (blockIdx.x > 0) {
        int e = e0 + ((int)blockIdx.x - 1) * 1024 + (int)threadIdx.x;
        if (e < e1) deg_edge(ei, ew, packed, eseq, ne, e);
        return;
    }
    __shared__ unsigned csum[1024];
    __shared__ float ps[DIM];
    int t = threadIdx.x;
    if (t < DIM) { float v = p[t]; ps[t] = v * v; }
    unsigned hv[16];
    unsigned s = 0;
#pragma unroll
    for (int j = 0; j < 16; ++j) {
        hv[j] = hist[hidx(t * 16 + j)];
        s += hv[j];
    }
    csum[t] = s;
    __syncthreads();
    if (t < 64) {
        for (int off = 64; off > 0; off >>= 1) {
            if (t < off) ps[t] += ps[t + off];
        }
    }
    if (t == 0) pinv[0] = 1.0f / sqrtf(ps[0] + ps[1]);   // tree leaves ps[0],ps[1] summed
    for (int off = 1; off < 1024; off <<= 1) {
        unsigned v = (t + off < 1024) ? csum[t + off] : 0u;
        __syncthreads();
        csum[t] += v;
        __syncthreads();
    }
    unsigned run = (t + 1 < 1024) ? csum[t + 1] : 0u;
#pragma unroll
    for (int j = 15; j >= 0; --j) {
        unsigned h = hv[j];
        if (h > 0u && run < (unsigned)k && run + h >= (unsigned)k) {
            binfo[0] = (unsigned)(t * 16 + j);
            binfo[1] = run;
        }
        run += h;
    }
}

__global__ void k_collect_deg(const float* __restrict__ score, const unsigned* __restrict__ binfo,
                              unsigned* __restrict__ counter, float* __restrict__ cval,
                              int* __restrict__ cidx, int n,
                              int degB, const int* __restrict__ ei, const float* __restrict__ ew,
                              unsigned long long* __restrict__ packed,
                              unsigned short* __restrict__ eseq,
                              int e0, int e1, int ne) {
    int mi, di;
    if (pick_deg((int)blockIdx.x, degB, (int)gridDim.x, &mi, &di)) {
        int e = e0 + di * 256 + (int)threadIdx.x;
        if (e < e1) deg_edge(ei, ew, packed, eseq, ne, e);
        return;
    }
    int i = mi * 256 + (int)threadIdx.x;
    if (i >= n) return;
    float s = score[i];
    if ((f2k(s) >> HSHIFT) >= binfo[0]) {
        unsigned pos = atomicAdd(counter, 1u);
        if (pos < CAP) { cval[pos] = s; cidx[pos] = i; }
    }
}

// rank-based exact top-k (matches jax.lax.top_k: desc, lower index wins ties)
__global__ void k_rank_deg(const float* __restrict__ cval, const int* __restrict__ cidx,
                           const unsigned* __restrict__ counter, int* __restrict__ perm,
                           float* __restrict__ vals, int k,
                           int degB, const int* __restrict__ ei, const float* __restrict__ ew,
                           unsigned long long* __restrict__ packed,
                           unsigned short* __restrict__ eseq,
                           int e0, int e1, int ne) {
    int mi, di;
    if (pick_deg((int)blockIdx.x, degB, (int)gridDim.x, &mi, &di)) {
        int e = e0 + di * 256 + (int)threadIdx.x;
        if (e < e1) deg_edge(ei, ew, packed, eseq, ne, e);
        return;
    }
    int i = mi * 256 + (int)threadIdx.x;
    unsigned cnt = counter[0];
    int m = (cnt < (unsigned)CAP) ? (int)cnt : CAP;
    if (i >= m) return;
    float v = cval[i]; int id = cidx[i];
    int rank = 0;
    for (int j = 0; j < m; ++j) {
        float vj = cval[j]; int ij = cidx[j];
        if (vj > v || (vj == v && ij < id)) ++rank;
    }
    if (rank < k) { perm[rank] = id; vals[rank] = v; }
}

// GRU with fused x_tilde (vals scaled by pinv here) + deg slice; writes W^T bf16
__global__ void k_gru_deg(const float* __restrict__ x, const int* __restrict__ perm,
                          const float* __restrict__ vals, const float* __restrict__ pinv,
                          const float* __restrict__ W0,
                          const float* __restrict__ w_ih, const float* __restrict__ w_hh,
                          const float* __restrict__ b_ih, const float* __restrict__ b_hh,
                          unsigned short* __restrict__ WhT,
                          int degB, const int* __restrict__ ei, const float* __restrict__ ew,
                          unsigned long long* __restrict__ packed,
                          unsigned short* __restrict__ eseq,
                          int e0, int e1, int ne) {
    __shared__ float sx[DIM], sh[DIM];
    int mi, di;
    if (pick_deg((int)blockIdx.x, degB, (int)gridDim.x, &mi, &di)) {
        int e = e0 + di * 128 + (int)threadIdx.x;
        if (e < e1) deg_edge(ei, ew, packed, eseq, ne, e);
        return;
    }
    int i = mi, c = threadIdx.x;
    sx[c] = x[(size_t)perm[i] * DIM + c] * tanhf(vals[i] * pinv[0]);
    sh[c] = W0[i * DIM + c];
    __syncthreads();
    float gr = b_ih[c], gz = b_ih[DIM + c], gn = b_ih[2 * DIM + c];
    float hr = b_hh[c], hz = b_hh[DIM + c], hn = b_hh[2 * DIM + c];
    const float* wr = w_ih + (size_t)c * DIM;
    const float* wz = w_ih + (size_t)(DIM + c) * DIM;
    const float* wn = w_ih + (size_t)(2 * DIM + c) * DIM;
    const float* ur = w_hh + (size_t)c * DIM;
    const float* uz = w_hh + (size_t)(DIM + c) * DIM;
    const float* un = w_hh + (size_t)(2 * DIM + c) * DIM;
    for (int d = 0; d < DIM; ++d) {
        float xd = sx[d], hd = sh[d];
        gr += xd * wr[d]; gz += xd * wz[d]; gn += xd * wn[d];
        hr += hd * ur[d]; hz += hd * uz[d]; hn += hd * un[d];
    }
    float r = 1.0f / (1.0f + expf(-(gr + hr)));
    float z = 1.0f / (1.0f + expf(-(gz + hz)));
    float nn = tanhf(gn + r * hn);
    float wv = (1.0f - z) * nn + z * sh[c];
    WhT[(size_t)c * DIM + i] = (unsigned short)bf16rn(wv);   // transposed bf16
}

// xw = x @ W -> bf16 via MFMA 16x16x32. 64x64 tile, 4 waves, 16KB LDS (bf16 x-tile,
// granule-XOR swizzle). W^T bf16 read from global (32KB, L2-resident).
__global__ __launch_bounds__(256) void k_xw_deg(const float* __restrict__ x,
                                                const unsigned short* __restrict__ WhT,
                                                unsigned short* __restrict__ xwh, int n,
                                                int degB, const int* __restrict__ ei,
                                                const float* __restrict__ ew,
                                                unsigned long long* __restrict__ packed,
                                                unsigned short* __restrict__ eseq,
                                                int e0, int e1, int ne) {
    __shared__ unsigned short xs[64 * DIM];   // 16KB: [r][k] bf16, granule g^=(r&7)
    int mi, di;
    if (pick_deg((int)blockIdx.x, degB, (int)gridDim.x, &mi, &di)) {
        int e = e0 + di * 256 + (int)threadIdx.x;
        if (e < e1) deg_edge(ei, ew, packed, eseq, ne, e);
        return;
    }
    int nTr = (n + 63) / 64;
    int r0 = (mi % nTr) * 64;
    int c0 = (mi / nTr) * 64;
    int t = threadIdx.x;
    {
        int r = t >> 2;
        int row = r0 + r; if (row >= n) row = n - 1;
        const float4* xr = (const float4*)(x + (size_t)row * DIM);
#pragma unroll
        for (int j = 0; j < 4; ++j) {
            int g = (t & 3) + 4 * j;
            float4 lo = xr[g * 2];
            float4 hi = xr[g * 2 + 1];
            uint4 o;
            o.x = pack2bf(lo.x, lo.y);
            o.y = pack2bf(lo.z, lo.w);
            o.z = pack2bf(hi.x, hi.y);
            o.w = pack2bf(hi.z, hi.w);
            *(uint4*)&xs[r * DIM + ((g ^ (r & 7)) << 3)] = o;
        }
    }
    __syncthreads();
    int wid = t >> 6, lane = t & 63;
    int lr = wid * 16 + (lane & 15);
    int kg = lane >> 4;
    int cA = lane & 15;
    f32x4 acc[4] = {{0.f,0.f,0.f,0.f},{0.f,0.f,0.f,0.f},{0.f,0.f,0.f,0.f},{0.f,0.f,0.f,0.f}};
    const bf16x8* wt = (const bf16x8*)WhT;
#pragma unroll
    for (int q = 0; q < 4; ++q) {
        bf16x8 a = *(const bf16x8*)&xs[lr * DIM + (((q * 4 + kg) ^ (lr & 7)) << 3)];
#pragma unroll
        for (int ct = 0; ct < 4; ++ct) {
            bf16x8 b = wt[(size_t)(c0 + ct * 16 + cA) * 16 + q * 4 + kg];
            acc[ct] = __builtin_amdgcn_mfma_f32_16x16x32_bf16(a, b, acc[ct], 0, 0, 0);
        }
    }
    int orow = r0 + wid * 16 + (lane >> 4) * 4;
#pragma unroll
    for (int reg = 0; reg < 4; ++reg) {
        int row = orow + reg;
        if (row < n) {
            unsigned short* dst = xwh + (size_t)row * DIM + c0 + cA;
#pragma unroll
            for (int ct = 0; ct < 4; ++ct)
                dst[ct * 16] = (unsigned short)bf16rn(acc[ct][reg]);
        }
    }
}

// fused: unpack packed -> dinv/cnt AND per-block partial sums for scan
__global__ void k_dinv_scan1(const unsigned long long* __restrict__ packed,
                             float* __restrict__ dinv, int* __restrict__ cnt,
                             int* __restrict__ bsum, int n) {
    __shared__ int red[256];
    int b = blockIdx.x, t = threadIdx.x;
    int chunk = (n + SCAN_B - 1) / SCAN_B;
    int lo = b * chunk;
    int hi = lo + chunk; if (hi > n) hi = n;
    int s = 0;
    for (int i = lo + t; i < hi; i += 256) {
        unsigned long long pk = packed[i];
        float sumw = (float)((double)(pk & ((1ull << 40) - 1ull)) * (1.0 / 4294967296.0));
        dinv[i] = rsqrtf(1.0f + sumw);
        int c = (int)(pk >> 40);
        cnt[i] = c;
        s += c;
    }
    red[t] = s;
    __syncthreads();
    for (int off = 128; off > 0; off >>= 1) {
        if (t < off) red[t] += red[t + off];
        __syncthreads();
    }
    if (t == 0) bsum[b] = red[0];
}

// fused scan2+scan3: each block locally scans bsum, then writes its offs chunk
__global__ void k_scan3f(const int* __restrict__ cnt, const int* __restrict__ bsum,
                         int* __restrict__ offs, int n) {
    __shared__ int sb[SCAN_B];
    __shared__ int red[256];
    int b = blockIdx.x, t = threadIdx.x;
    sb[t] = bsum[t];
    __syncthreads();
    for (int off = 1; off < SCAN_B; off <<= 1) {
        int v = (t >= off) ? sb[t - off] : 0;
        __syncthreads();
        sb[t] += v;
        __syncthreads();
    }
    int bbase = (b > 0) ? sb[b - 1] : 0;
    int total = sb[SCAN_B - 1];
    int chunk = (n + SCAN_B - 1) / SCAN_B;
    int lo = b * chunk;
    int hi = lo + chunk; if (hi > n) hi = n;
    int tchunk = (chunk + 255) / 256;
    int tlo = lo + t * tchunk;
    int thi = tlo + tchunk; if (thi > hi) thi = hi;
    int s = 0;
    for (int i = tlo; i < thi; ++i) s += cnt[i];
    red[t] = s;
    __syncthreads();
    for (int off = 1; off < 256; off <<= 1) {
        int v = (t >= off) ? red[t - off] : 0;
        __syncthreads();
        red[t] += v;
        __syncthreads();
    }
    int run = bbase + ((t > 0) ? red[t - 1] : 0);
    for (int i = tlo; i < thi; ++i) {
        offs[i] = run; run += cnt[i];
    }
    if (b == 0 && t == 0) offs[n] = total;
}

// bucket edges by destination, atomic-free: pos = offs[c] + eseq[e]
__global__ void k_fill(const int* __restrict__ ei, const float* __restrict__ ew,
                       const float* __restrict__ dinv, const int* __restrict__ offs,
                       const unsigned short* __restrict__ eseq, int2* __restrict__ edata, int ne) {
    int e = blockIdx.x * blockDim.x + threadIdx.x;
    if (e >= ne) return;
    int r = ei[e], c = ei[ne + e];
    float nrm = dinv[r] * ew[e] * dinv[c];
    int pos = offs[c] + (int)eseq[e];
    edata[pos] = make_int2(r, __float_as_int(nrm));
}

// per-node gather + fused relu-linear head: 16 lanes per node, 8 bf16 (16B) each.
// FULL-BATCH (16-deep) load clustering for maximum memory-level parallelism.
__global__ __launch_bounds__(256) void k_gather(const unsigned short* __restrict__ xwh,
        const float* __restrict__ dinv, const int* __restrict__ offs,
        const int2* __restrict__ edata, const float* __restrict__ w_lin,
        const float* __restrict__ b_lin, float* __restrict__ out, int n) {
    int gid = blockIdx.x * 256 + threadIdx.x;
    int c = gid >> 4, lane = gid & 15;
    if (c >= n) return;
    const uint4* xw4 = (const uint4*)xwh;
    float dd = dinv[c]; dd *= dd;
    float acc[8];
    {
        uint4 a = xw4[(size_t)c * 16 + lane];
        unsigned w[4] = {a.x, a.y, a.z, a.w};
#pragma unroll
        for (int q = 0; q < 4; ++q) {
            acc[2 * q]     = __uint_as_float(w[q] << 16) * dd;
            acc[2 * q + 1] = __uint_as_float(w[q] & 0xffff0000u) * dd;
        }
    }
    int start = offs[c], end = offs[c + 1];
    for (int base = start; base < end; base += 16) {
        int m = end - base; if (m > 16) m = 16;
        int2 ed = (base + lane < end) ? edata[base + lane] : make_int2(0, 0);
        uint4 v[16]; float nr[16];
#pragma unroll
        for (int jj = 0; jj < 16; ++jj) {
            int src = __shfl(ed.x, jj, 16);
            nr[jj] = (jj < m) ? __int_as_float(__shfl(ed.y, jj, 16)) : 0.0f;
            v[jj] = xw4[(size_t)src * 16 + lane];
        }
#pragma unroll
        for (int jj = 0; jj < 16; ++jj) {
            unsigned w[4] = {v[jj].x, v[jj].y, v[jj].z, v[jj].w};
#pragma unroll
            for (int q = 0; q < 4; ++q) {
                acc[2 * q]     += __uint_as_float(w[q] << 16) * nr[jj];
                acc[2 * q + 1] += __uint_as_float(w[q] & 0xffff0000u) * nr[jj];
            }
        }
    }
    float4 wla = ((const float4*)w_lin)[lane * 2];
    float4 wlb = ((const float4*)w_lin)[lane * 2 + 1];
    float r = fmaxf(acc[0], 0.0f) * wla.x + fmaxf(acc[1], 0.0f) * wla.y +
              fmaxf(acc[2], 0.0f) * wla.z + fmaxf(acc[3], 0.0f) * wla.w +
              fmaxf(acc[4], 0.0f) * wlb.x + fmaxf(acc[5], 0.0f) * wlb.y +
              fmaxf(acc[6], 0.0f) * wlb.z + fmaxf(acc[7], 0.0f) * wlb.w;
#pragma unroll
    for (int m = 8; m >= 1; m >>= 1) r += __shfl_xor(r, m, 16);
    if (lane == 0) out[c] = r + b_lin[0];
}

extern "C" void kernel_launch(void* const* d_in, const int* in_sizes, int n_in,
                              void* d_out, int out_size, void* d_ws, size_t ws_size,
                              hipStream_t stream) {
    const float* x     = (const float*)d_in[0];
    const int*   ei    = (const int*)d_in[1];
    const float* ew    = (const float*)d_in[2];
    const float* p     = (const float*)d_in[3];
    const float* W0    = (const float*)d_in[4];
    const float* w_ih  = (const float*)d_in[5];
    const float* w_hh  = (const float*)d_in[6];
    const float* b_ih  = (const float*)d_in[7];
    const float* b_hh  = (const float*)d_in[8];
    const float* w_lin = (const float*)d_in[9];
    const float* b_lin = (const float*)d_in[10];
    float* out = (float*)d_out;
    int n  = in_sizes[0] / DIM;
    int ne = in_sizes[2];
    (void)n_in; (void)out_size; (void)ws_size;

    char* base = (char*)d_ws;
    size_t o = 0;
    auto alloc = [&](size_t b) { size_t r = o; o += (b + 255) & ~(size_t)255; return r; };
    // packed+hist+counter contiguous -> single async memset zeroes all three
    size_t zero_beg = o;
    unsigned long long* packed = (unsigned long long*)(base + alloc((size_t)n * 8));
    unsigned* hist    = (unsigned*)(base + alloc(HSIZE * 4));
    unsigned* counter = (unsigned*)(base + alloc(256));
    size_t zero_len = o - zero_beg;
    float*    score   = (float*)(base + alloc((size_t)n * 4));
    unsigned* binfo   = (unsigned*)(base + alloc(256));
    float*    cval    = (float*)(base + alloc((size_t)CAP * 4));
    int*      cidx    = (int*)(base + alloc((size_t)CAP * 4));
    int*      perm    = (int*)(base + alloc(TOPK * 4));
    float*    vals    = (float*)(base + alloc(TOPK * 4));
    float*    pinv    = (float*)(base + alloc(256));
    unsigned short* WhT = (unsigned short*)(base + alloc(DIM * DIM * 2));
    float*    dinv    = (float*)(base + alloc((size_t)n * 4));
    int*      cnt     = (int*)(base + alloc((size_t)n * 4));
    int*      offs    = (int*)(base + alloc((size_t)(n + 1) * 4));
    unsigned short* eseq = (unsigned short*)(base + alloc((size_t)ne * 2));
    int*      bsum    = (int*)(base + alloc((SCAN_B + 1) * 4));
    int2*     edata   = (int2*)(base + alloc((size_t)ne * 8));
    unsigned short* xwh = (unsigned short*)(base + alloc((size_t)n * DIM * 2));

    // edge-slice assignment proportional to carriers' native durations
    struct Slice { int e0, e1, blocks; };
    int cur = 0;
    auto take = [&](int want, int bs) {
        Slice s; s.e0 = cur;
        int t = want; if (cur + t > ne) t = ne - cur;
        s.e1 = cur + t; cur = s.e1;
        s.blocks = (t + bs - 1) / bs;
        return s;
    };
    Slice sl_score = take(330000, 256);
    Slice sl_fb    = take(180000, 1024);
    Slice sl_col   = take(130000, 256);
    Slice sl_rank  = take(90000, 256);
    Slice sl_gru   = take(330000, 128);
    Slice sl_xw    = take(ne, 256);        // remainder (~540k)

    int scoreMB = (n * 16 + 255) / 256;
    int colMB   = (n + 255) / 256;
    int xwMB    = ((n + 63) / 64) * 2;

    hipMemsetAsync(base + zero_beg, 0, zero_len, stream);
    k_score_deg<<<scoreMB + sl_score.blocks, 256, 0, stream>>>(
        x, p, score, hist, n, sl_score.blocks, ei, ew, packed, eseq,
        sl_score.e0, sl_score.e1, ne);
    k_findbin_deg<<<1 + sl_fb.blocks, 1024, 0, stream>>>(
        hist, binfo, TOPK, p, pinv, ei, ew, packed, eseq, sl_fb.e0, sl_fb.e1, ne);
    k_collect_deg<<<colMB + sl_col.blocks, 256, 0, stream>>>(
        score, binfo, counter, cval, cidx, n, sl_col.blocks, ei, ew, packed, eseq,
        sl_col.e0, sl_col.e1, ne);
    k_rank_deg<<<(CAP / 256) + sl_rank.blocks, 256, 0, stream>>>(
        cval, cidx, counter, perm, vals, TOPK, sl_rank.blocks, ei, ew, packed, eseq,
        sl_rank.e0, sl_rank.e1, ne);
    k_gru_deg<<<DIM + sl_gru.blocks, 128, 0, stream>>>(
        x, perm, vals, pinv, W0, w_ih, w_hh, b_ih, b_hh, WhT, sl_gru.blocks, ei, ew,
        packed, eseq, sl_gru.e0, sl_gru.e1, ne);
    k_xw_deg<<<xwMB + sl_xw.blocks, 256, 0, stream>>>(
        x, WhT, xwh, n, sl_xw.blocks, ei, ew, packed, eseq, sl_xw.e0, sl_xw.e1, ne);
    k_dinv_scan1<<<SCAN_B, 256, 0, stream>>>(packed, dinv, cnt, bsum, n);
    k_scan3f<<<SCAN_B, 256, 0, stream>>>(cnt, bsum, offs, n);
    k_fill<<<(ne + 255) / 256, 256, 0, stream>>>(ei, ew, dinv, offs, eseq, edata, ne);
    long long g_threads = (long long)n * 16;
    k_gather<<<(int)((g_threads + 255) / 256), 256, 0, stream>>>(
        xwh, dinv, offs, edata, w_lin, b_lin, out, n);
}

// Round 16
// 239.305 us; speedup vs baseline: 2.8388x; 1.0097x over previous
//
#include <hip/hip_runtime.h>
#include <hip/hip_bf16.h>
#include <math.h>

#define DIM 128
#define TOPK 128
#define CAP 4096
#define SCAN_B 256
#define HSIZE 16384
#define HSHIFT 18          // f2k >> 18 -> 14-bit bin
#define HMUL 10937u        // odd -> bijective mod 2^14

typedef __attribute__((ext_vector_type(8))) short bf16x8;
typedef __attribute__((ext_vector_type(4))) float f32x4;

__device__ __forceinline__ unsigned f2k(float f) {
    unsigned b = __float_as_uint(f);
    return (b & 0x80000000u) ? ~b : (b | 0x80000000u);
}

__device__ __forceinline__ unsigned hidx(unsigned bin) {
    return (bin * HMUL) & (HSIZE - 1u);
}

// round-to-nearest-even bf16 (as high 16 bits of fp32)
__device__ __forceinline__ unsigned bf16rn(float v) {
    unsigned u = __float_as_uint(v);
    u += 0x7fffu + ((u >> 16) & 1u);
    return u >> 16;
}

__device__ __forceinline__ unsigned pack2bf(float lo, float hi) {
    return (bf16rn(hi) << 16) | bf16rn(lo);
}

// one u64 atomic per edge: [63:40] count, [39:0] fixed-point weight sum (2^-32).
__device__ __forceinline__ void deg_edge(const int* __restrict__ ei, const float* __restrict__ ew,
                                         unsigned long long* __restrict__ packed,
                                         unsigned short* __restrict__ eseq, int ne, int e) {
    int c = ei[ne + e];
    float w = ew[e];
    unsigned long long fx = (unsigned long long)((double)w * 4294967296.0);
    unsigned long long old = atomicAdd(&packed[c], (1ull << 40) | fx);
    eseq[e] = (unsigned short)(old >> 40);
}

// Bresenham interleave of degB deg-blocks among T total blocks.
__device__ __forceinline__ bool pick_deg(int bid, int degB, int T, int* mi, int* di) {
    long long a = (long long)bid * degB;
    int before = (int)(a / T);
    if ((int)((a + degB) / T) > before) { *di = before; return true; }
    *mi = bid - before;
    return false;
}

// 16 lanes per node (2x float4 each): UNSCALED score + spread-hist bin, + deg slice
__global__ void k_score_deg(const float* __restrict__ x, const float* __restrict__ p,
                            float* __restrict__ score,
                            unsigned* __restrict__ hist, int n,
                            int degB, const int* __restrict__ ei, const float* __restrict__ ew,
                            unsigned long long* __restrict__ packed,
                            unsigned short* __restrict__ eseq,
                            int e0, int e1, int ne) {
    int mi, di;
    if (pick_deg((int)blockIdx.x, degB, (int)gridDim.x, &mi, &di)) {
        int e = e0 + di * 256 + (int)threadIdx.x;
        if (e < e1) deg_edge(ei, ew, packed, eseq, ne, e);
        return;
    }
    int gid = mi * 256 + (int)threadIdx.x;
    int node = gid >> 4, lane = gid & 15;
    if (node >= n) return;
    const float4* xr = (const float4*)(x) + (size_t)node * 32;
    const float4* p4 = (const float4*)p;
    float4 a0 = xr[lane * 2], a1 = xr[lane * 2 + 1];
    float4 b0 = p4[lane * 2], b1 = p4[lane * 2 + 1];
    float acc = a0.x * b0.x + a0.y * b0.y + a0.z * b0.z + a0.w * b0.w +
                a1.x * b1.x + a1.y * b1.y + a1.z * b1.z + a1.w * b1.w;
#pragma unroll
    for (int m = 8; m >= 1; m >>= 1) acc += __shfl_xor(acc, m, 16);
    if (lane == 0) {
        score[node] = acc;                     // raw dot; ordering is scale-invariant
        atomicAdd(&hist[hidx(f2k(acc) >> HSHIFT)], 1u);
    }
}

// block 0: find threshold bin (16 bins/thread) + compute pinv; other blocks: deg slice
__global__ void k_findbin_deg(const unsigned* __restrict__ hist, unsigned* __restrict__ binfo,
                              int k, const float* __restrict__ p, float* __restrict__ pinv,
                              const int* __restrict__ ei, const float* __restrict__ ew,
                              unsigned long long* __restrict__ packed,
                              unsigned short* __restrict__ eseq,
                              int e0, int e1, int ne) {
    if (blockIdx.x > 0) {
        int e = e0 + ((int)blockIdx.x - 1) * 1024 + (int)threadIdx.x;
        if (e < e1) deg_edge(ei, ew, packed, eseq, ne, e);
        return;
    }
    __shared__ unsigned csum[1024];
    __shared__ float ps[DIM];
    int t = threadIdx.x;
    if (t < DIM) { float v = p[t]; ps[t] = v * v; }
    unsigned hv[16];
    unsigned s = 0;
#pragma unroll
    for (int j = 0; j < 16; ++j) {
        hv[j] = hist[hidx(t * 16 + j)];
        s += hv[j];
    }
    csum[t] = s;
    __syncthreads();
    if (t < 64) {
        for (int off = 64; off > 0; off >>= 1) {
            if (t < off) ps[t] += ps[t + off];
        }
    }
    if (t == 0) pinv[0] = 1.0f / sqrtf(ps[0] + ps[1]);   // tree leaves ps[0],ps[1] summed
    for (int off = 1; off < 1024; off <<= 1) {
        unsigned v = (t + off < 1024) ? csum[t + off] : 0u;
        __syncthreads();
        csum[t] += v;
        __syncthreads();
    }
    unsigned run = (t + 1 < 1024) ? csum[t + 1] : 0u;
#pragma unroll
    for (int j = 15; j >= 0; --j) {
        unsigned h = hv[j];
        if (h > 0u && run < (unsigned)k && run + h >= (unsigned)k) {
            binfo[0] = (unsigned)(t * 16 + j);
            binfo[1] = run;
        }
        run += h;
    }
}

__global__ void k_collect_deg(const float* __restrict__ score, const unsigned* __restrict__ binfo,
                              unsigned* __restrict__ counter, float* __restrict__ cval,
                              int* __restrict__ cidx, int n,
                              int degB, const int* __restrict__ ei, const float* __restrict__ ew,
                              unsigned long long* __restrict__ packed,
                              unsigned short* __restrict__ eseq,
                              int e0, int e1, int ne) {
    int mi, di;
    if (pick_deg((int)blockIdx.x, degB, (int)gridDim.x, &mi, &di)) {
        int e = e0 + di * 256 + (int)threadIdx.x;
        if (e < e1) deg_edge(ei, ew, packed, eseq, ne, e);
        return;
    }
    int i = mi * 256 + (int)threadIdx.x;
    if (i >= n) return;
    float s = score[i];
    if ((f2k(s) >> HSHIFT) >= binfo[0]) {
        unsigned pos = atomicAdd(counter, 1u);
        if (pos < CAP) { cval[pos] = s; cidx[pos] = i; }
    }
}

// rank-based exact top-k (matches jax.lax.top_k: desc, lower index wins ties)
__global__ void k_rank_deg(const float* __restrict__ cval, const int* __restrict__ cidx,
                           const unsigned* __restrict__ counter, int* __restrict__ perm,
                           float* __restrict__ vals, int k,
                           int degB, const int* __restrict__ ei, const float* __restrict__ ew,
                           unsigned long long* __restrict__ packed,
                           unsigned short* __restrict__ eseq,
                           int e0, int e1, int ne) {
    int mi, di;
    if (pick_deg((int)blockIdx.x, degB, (int)gridDim.x, &mi, &di)) {
        int e = e0 + di * 256 + (int)threadIdx.x;
        if (e < e1) deg_edge(ei, ew, packed, eseq, ne, e);
        return;
    }
    int i = mi * 256 + (int)threadIdx.x;
    unsigned cnt = counter[0];
    int m = (cnt < (unsigned)CAP) ? (int)cnt : CAP;
    if (i >= m) return;
    float v = cval[i]; int id = cidx[i];
    int rank = 0;
    for (int j = 0; j < m; ++j) {
        float vj = cval[j]; int ij = cidx[j];
        if (vj > v || (vj == v && ij < id)) ++rank;
    }
    if (rank < k) { perm[rank] = id; vals[rank] = v; }
}

// GRU with fused x_tilde (vals scaled by pinv here) + deg slice; writes W^T bf16
__global__ void k_gru_deg(const float* __restrict__ x, const int* __restrict__ perm,
                          const float* __restrict__ vals, const float* __restrict__ pinv,
                          const float* __restrict__ W0,
                          const float* __restrict__ w_ih, const float* __restrict__ w_hh,
                          const float* __restrict__ b_ih, const float* __restrict__ b_hh,
                          unsigned short* __restrict__ WhT,
                          int degB, const int* __restrict__ ei, const float* __restrict__ ew,
                          unsigned long long* __restrict__ packed,
                          unsigned short* __restrict__ eseq,
                          int e0, int e1, int ne) {
    __shared__ float sx[DIM], sh[DIM];
    int mi, di;
    if (pick_deg((int)blockIdx.x, degB, (int)gridDim.x, &mi, &di)) {
        int e = e0 + di * 128 + (int)threadIdx.x;
        if (e < e1) deg_edge(ei, ew, packed, eseq, ne, e);
        return;
    }
    int i = mi, c = threadIdx.x;
    sx[c] = x[(size_t)perm[i] * DIM + c] * tanhf(vals[i] * pinv[0]);
    sh[c] = W0[i * DIM + c];
    __syncthreads();
    float gr = b_ih[c], gz = b_ih[DIM + c], gn = b_ih[2 * DIM + c];
    float hr = b_hh[c], hz = b_hh[DIM + c], hn = b_hh[2 * DIM + c];
    const float* wr = w_ih + (size_t)c * DIM;
    const float* wz = w_ih + (size_t)(DIM + c) * DIM;
    const float* wn = w_ih + (size_t)(2 * DIM + c) * DIM;
    const float* ur = w_hh + (size_t)c * DIM;
    const float* uz = w_hh + (size_t)(DIM + c) * DIM;
    const float* un = w_hh + (size_t)(2 * DIM + c) * DIM;
    for (int d = 0; d < DIM; ++d) {
        float xd = sx[d], hd = sh[d];
        gr += xd * wr[d]; gz += xd * wz[d]; gn += xd * wn[d];
        hr += hd * ur[d]; hz += hd * uz[d]; hn += hd * un[d];
    }
    float r = 1.0f / (1.0f + expf(-(gr + hr)));
    float z = 1.0f / (1.0f + expf(-(gz + hz)));
    float nn = tanhf(gn + r * hn);
    float wv = (1.0f - z) * nn + z * sh[c];
    WhT[(size_t)c * DIM + i] = (unsigned short)bf16rn(wv);   // transposed bf16
}

// xw = x @ W -> bf16 via MFMA 16x16x32. 64x64 tile, 4 waves, 16KB LDS (bf16 x-tile,
// granule-XOR swizzle). W^T bf16 read from global (32KB, L2-resident).
__global__ __launch_bounds__(256) void k_xw_deg(const float* __restrict__ x,
                                                const unsigned short* __restrict__ WhT,
                                                unsigned short* __restrict__ xwh, int n,
                                                int degB, const int* __restrict__ ei,
                                                const float* __restrict__ ew,
                                                unsigned long long* __restrict__ packed,
                                                unsigned short* __restrict__ eseq,
                                                int e0, int e1, int ne) {
    __shared__ unsigned short xs[64 * DIM];   // 16KB: [r][k] bf16, granule g^=(r&7)
    int mi, di;
    if (pick_deg((int)blockIdx.x, degB, (int)gridDim.x, &mi, &di)) {
        int e = e0 + di * 256 + (int)threadIdx.x;
        if (e < e1) deg_edge(ei, ew, packed, eseq, ne, e);
        return;
    }
    int nTr = (n + 63) / 64;
    int r0 = (mi % nTr) * 64;
    int c0 = (mi / nTr) * 64;
    int t = threadIdx.x;
    {
        int r = t >> 2;
        int row = r0 + r; if (row >= n) row = n - 1;
        const float4* xr = (const float4*)(x + (size_t)row * DIM);
#pragma unroll
        for (int j = 0; j < 4; ++j) {
            int g = (t & 3) + 4 * j;
            float4 lo = xr[g * 2];
            float4 hi = xr[g * 2 + 1];
            uint4 o;
            o.x = pack2bf(lo.x, lo.y);
            o.y = pack2bf(lo.z, lo.w);
            o.z = pack2bf(hi.x, hi.y);
            o.w = pack2bf(hi.z, hi.w);
            *(uint4*)&xs[r * DIM + ((g ^ (r & 7)) << 3)] = o;
        }
    }
    __syncthreads();
    int wid = t >> 6, lane = t & 63;
    int lr = wid * 16 + (lane & 15);
    int kg = lane >> 4;
    int cA = lane & 15;
    f32x4 acc[4] = {{0.f,0.f,0.f,0.f},{0.f,0.f,0.f,0.f},{0.f,0.f,0.f,0.f},{0.f,0.f,0.f,0.f}};
    const bf16x8* wt = (const bf16x8*)WhT;
#pragma unroll
    for (int q = 0; q < 4; ++q) {
        bf16x8 a = *(const bf16x8*)&xs[lr * DIM + (((q * 4 + kg) ^ (lr & 7)) << 3)];
#pragma unroll
        for (int ct = 0; ct < 4; ++ct) {
            bf16x8 b = wt[(size_t)(c0 + ct * 16 + cA) * 16 + q * 4 + kg];
            acc[ct] = __builtin_amdgcn_mfma_f32_16x16x32_bf16(a, b, acc[ct], 0, 0, 0);
        }
    }
    int orow = r0 + wid * 16 + (lane >> 4) * 4;
#pragma unroll
    for (int reg = 0; reg < 4; ++reg) {
        int row = orow + reg;
        if (row < n) {
            unsigned short* dst = xwh + (size_t)row * DIM + c0 + cA;
#pragma unroll
            for (int ct = 0; ct < 4; ++ct)
                dst[ct * 16] = (unsigned short)bf16rn(acc[ct][reg]);
        }
    }
}

// fused: unpack packed -> dinv/cnt AND per-block partial sums for scan
__global__ void k_dinv_scan1(const unsigned long long* __restrict__ packed,
                             float* __restrict__ dinv, int* __restrict__ cnt,
                             int* __restrict__ bsum, int n) {
    __shared__ int red[256];
    int b = blockIdx.x, t = threadIdx.x;
    int chunk = (n + SCAN_B - 1) / SCAN_B;
    int lo = b * chunk;
    int hi = lo + chunk; if (hi > n) hi = n;
    int s = 0;
    for (int i = lo + t; i < hi; i += 256) {
        unsigned long long pk = packed[i];
        float sumw = (float)((double)(pk & ((1ull << 40) - 1ull)) * (1.0 / 4294967296.0));
        dinv[i] = rsqrtf(1.0f + sumw);
        int c = (int)(pk >> 40);
        cnt[i] = c;
        s += c;
    }
    red[t] = s;
    __syncthreads();
    for (int off = 128; off > 0; off >>= 1) {
        if (t < off) red[t] += red[t + off];
        __syncthreads();
    }
    if (t == 0) bsum[b] = red[0];
}

// fused scan2+scan3: each block locally scans bsum, then writes its offs chunk
__global__ void k_scan3f(const int* __restrict__ cnt, const int* __restrict__ bsum,
                         int* __restrict__ offs, int n) {
    __shared__ int sb[SCAN_B];
    __shared__ int red[256];
    int b = blockIdx.x, t = threadIdx.x;
    sb[t] = bsum[t];
    __syncthreads();
    for (int off = 1; off < SCAN_B; off <<= 1) {
        int v = (t >= off) ? sb[t - off] : 0;
        __syncthreads();
        sb[t] += v;
        __syncthreads();
    }
    int bbase = (b > 0) ? sb[b - 1] : 0;
    int total = sb[SCAN_B - 1];
    int chunk = (n + SCAN_B - 1) / SCAN_B;
    int lo = b * chunk;
    int hi = lo + chunk; if (hi > n) hi = n;
    int tchunk = (chunk + 255) / 256;
    int tlo = lo + t * tchunk;
    int thi = tlo + tchunk; if (thi > hi) thi = hi;
    int s = 0;
    for (int i = tlo; i < thi; ++i) s += cnt[i];
    red[t] = s;
    __syncthreads();
    for (int off = 1; off < 256; off <<= 1) {
        int v = (t >= off) ? red[t - off] : 0;
        __syncthreads();
        red[t] += v;
        __syncthreads();
    }
    int run = bbase + ((t > 0) ? red[t - 1] : 0);
    for (int i = tlo; i < thi; ++i) {
        offs[i] = run; run += cnt[i];
    }
    if (b == 0 && t == 0) offs[n] = total;
}

// bucket edges by destination, atomic-free: pos = offs[c] + eseq[e]
__global__ void k_fill(const int* __restrict__ ei, const float* __restrict__ ew,
                       const float* __restrict__ dinv, const int* __restrict__ offs,
                       const unsigned short* __restrict__ eseq, int2* __restrict__ edata, int ne) {
    int e = blockIdx.x * blockDim.x + threadIdx.x;
    if (e >= ne) return;
    int r = ei[e], c = ei[ne + e];
    float nrm = dinv[r] * ew[e] * dinv[c];
    int pos = offs[c] + (int)eseq[e];
    edata[pos] = make_int2(r, __float_as_int(nrm));
}

// per-node gather + fused relu-linear head: 16 lanes per node, 8 bf16 (16B) each.
// 8-deep load clustering (40 VGPR, high occupancy — TLP beats deeper ILP here).
__global__ __launch_bounds__(256) void k_gather(const unsigned short* __restrict__ xwh,
        const float* __restrict__ dinv, const int* __restrict__ offs,
        const int2* __restrict__ edata, const float* __restrict__ w_lin,
        const float* __restrict__ b_lin, float* __restrict__ out, int n) {
    int gid = blockIdx.x * 256 + threadIdx.x;
    int c = gid >> 4, lane = gid & 15;
    if (c >= n) return;
    const uint4* xw4 = (const uint4*)xwh;
    float dd = dinv[c]; dd *= dd;
    float acc[8];
    {
        uint4 a = xw4[(size_t)c * 16 + lane];
        unsigned w[4] = {a.x, a.y, a.z, a.w};
#pragma unroll
        for (int q = 0; q < 4; ++q) {
            acc[2 * q]     = __uint_as_float(w[q] << 16) * dd;
            acc[2 * q + 1] = __uint_as_float(w[q] & 0xffff0000u) * dd;
        }
    }
    int start = offs[c], end = offs[c + 1];
    for (int base = start; base < end; base += 16) {
        int m = end - base; if (m > 16) m = 16;
        int2 ed = (base + lane < end) ? edata[base + lane] : make_int2(0, 0);
        for (int j0 = 0; j0 < m; j0 += 8) {
            uint4 v[8]; float nr[8];
#pragma unroll
            for (int jj = 0; jj < 8; ++jj) {
                int j = j0 + jj;
                int src = __shfl(ed.x, j & 15, 16);
                nr[jj] = (j < m) ? __int_as_float(__shfl(ed.y, j & 15, 16)) : 0.0f;
                v[jj] = xw4[(size_t)src * 16 + lane];
            }
#pragma unroll
            for (int jj = 0; jj < 8; ++jj) {
                unsigned w[4] = {v[jj].x, v[jj].y, v[jj].z, v[jj].w};
#pragma unroll
                for (int q = 0; q < 4; ++q) {
                    acc[2 * q]     += __uint_as_float(w[q] << 16) * nr[jj];
                    acc[2 * q + 1] += __uint_as_float(w[q] & 0xffff0000u) * nr[jj];
                }
            }
        }
    }
    float4 wla = ((const float4*)w_lin)[lane * 2];
    float4 wlb = ((const float4*)w_lin)[lane * 2 + 1];
    float r = fmaxf(acc[0], 0.0f) * wla.x + fmaxf(acc[1], 0.0f) * wla.y +
              fmaxf(acc[2], 0.0f) * wla.z + fmaxf(acc[3], 0.0f) * wla.w +
              fmaxf(acc[4], 0.0f) * wlb.x + fmaxf(acc[5], 0.0f) * wlb.y +
              fmaxf(acc[6], 0.0f) * wlb.z + fmaxf(acc[7], 0.0f) * wlb.w;
#pragma unroll
    for (int m = 8; m >= 1; m >>= 1) r += __shfl_xor(r, m, 16);
    if (lane == 0) out[c] = r + b_lin[0];
}

extern "C" void kernel_launch(void* const* d_in, const int* in_sizes, int n_in,
                              void* d_out, int out_size, void* d_ws, size_t ws_size,
                              hipStream_t stream) {
    const float* x     = (const float*)d_in[0];
    const int*   ei    = (const int*)d_in[1];
    const float* ew    = (const float*)d_in[2];
    const float* p     = (const float*)d_in[3];
    const float* W0    = (const float*)d_in[4];
    const float* w_ih  = (const float*)d_in[5];
    const float* w_hh  = (const float*)d_in[6];
    const float* b_ih  = (const float*)d_in[7];
    const float* b_hh  = (const float*)d_in[8];
    const float* w_lin = (const float*)d_in[9];
    const float* b_lin = (const float*)d_in[10];
    float* out = (float*)d_out;
    int n  = in_sizes[0] / DIM;
    int ne = in_sizes[2];
    (void)n_in; (void)out_size; (void)ws_size;

    char* base = (char*)d_ws;
    size_t o = 0;
    auto alloc = [&](size_t b) { size_t r = o; o += (b + 255) & ~(size_t)255; return r; };
    // packed+hist+counter contiguous -> single async memset zeroes all three
    size_t zero_beg = o;
    unsigned long long* packed = (unsigned long long*)(base + alloc((size_t)n * 8));
    unsigned* hist    = (unsigned*)(base + alloc(HSIZE * 4));
    unsigned* counter = (unsigned*)(base + alloc(256));
    size_t zero_len = o - zero_beg;
    float*    score   = (float*)(base + alloc((size_t)n * 4));
    unsigned* binfo   = (unsigned*)(base + alloc(256));
    float*    cval    = (float*)(base + alloc((size_t)CAP * 4));
    int*      cidx    = (int*)(base + alloc((size_t)CAP * 4));
    int*      perm    = (int*)(base + alloc(TOPK * 4));
    float*    vals    = (float*)(base + alloc(TOPK * 4));
    float*    pinv    = (float*)(base + alloc(256));
    unsigned short* WhT = (unsigned short*)(base + alloc(DIM * DIM * 2));
    float*    dinv    = (float*)(base + alloc((size_t)n * 4));
    int*      cnt     = (int*)(base + alloc((size_t)n * 4));
    int*      offs    = (int*)(base + alloc((size_t)(n + 1) * 4));
    unsigned short* eseq = (unsigned short*)(base + alloc((size_t)ne * 2));
    int*      bsum    = (int*)(base + alloc((SCAN_B + 1) * 4));
    int2*     edata   = (int2*)(base + alloc((size_t)ne * 8));
    unsigned short* xwh = (unsigned short*)(base + alloc((size_t)n * DIM * 2));

    // edge-slice assignment proportional to carriers' native durations
    struct Slice { int e0, e1, blocks; };
    int cur = 0;
    auto take = [&](int want, int bs) {
        Slice s; s.e0 = cur;
        int t = want; if (cur + t > ne) t = ne - cur;
        s.e1 = cur + t; cur = s.e1;
        s.blocks = (t + bs - 1) / bs;
        return s;
    };
    Slice sl_score = take(330000, 256);
    Slice sl_fb    = take(180000, 1024);
    Slice sl_col   = take(130000, 256);
    Slice sl_rank  = take(90000, 256);
    Slice sl_gru   = take(330000, 128);
    Slice sl_xw    = take(ne, 256);        // remainder (~540k)

    int scoreMB = (n * 16 + 255) / 256;
    int colMB   = (n + 255) / 256;
    int xwMB    = ((n + 63) / 64) * 2;

    hipMemsetAsync(base + zero_beg, 0, zero_len, stream);
    k_score_deg<<<scoreMB + sl_score.blocks, 256, 0, stream>>>(
        x, p, score, hist, n, sl_score.blocks, ei, ew, packed, eseq,
        sl_score.e0, sl_score.e1, ne);
    k_findbin_deg<<<1 + sl_fb.blocks, 1024, 0, stream>>>(
        hist, binfo, TOPK, p, pinv, ei, ew, packed, eseq, sl_fb.e0, sl_fb.e1, ne);
    k_collect_deg<<<colMB + sl_col.blocks, 256, 0, stream>>>(
        score, binfo, counter, cval, cidx, n, sl_col.blocks, ei, ew, packed, eseq,
        sl_col.e0, sl_col.e1, ne);
    k_rank_deg<<<(CAP / 256) + sl_rank.blocks, 256, 0, stream>>>(
        cval, cidx, counter, perm, vals, TOPK, sl_rank.blocks, ei, ew, packed, eseq,
        sl_rank.e0, sl_rank.e1, ne);
    k_gru_deg<<<DIM + sl_gru.blocks, 128, 0, stream>>>(
        x, perm, vals, pinv, W0, w_ih, w_hh, b_ih, b_hh, WhT, sl_gru.blocks, ei, ew,
        packed, eseq, sl_gru.e0, sl_gru.e1, ne);
    k_xw_deg<<<xwMB + sl_xw.blocks, 256, 0, stream>>>(
        x, WhT, xwh, n, sl_xw.blocks, ei, ew, packed, eseq, sl_xw.e0, sl_xw.e1, ne);
    k_dinv_scan1<<<SCAN_B, 256, 0, stream>>>(packed, dinv, cnt, bsum, n);
    k_scan3f<<<SCAN_B, 256, 0, stream>>>(cnt, bsum, offs, n);
    k_fill<<<(ne + 255) / 256, 256, 0, stream>>>(ei, ew, dinv, offs, eseq, edata, ne);
    long long g_threads = (long long)n * 16;
    k_gather<<<(int)((g_threads + 255) / 256), 256, 0, stream>>>(
        xwh, dinv, offs, edata, w_lin, b_lin, out, n);
}